// Round 8
// baseline (275.561 us; speedup 1.0000x reference)
//
#include <hip/hip_runtime.h>

#define N_NODES 50000
#define N_INC   300000
#define DIM     256
#define M_EDGES 20000
#define NEG_SLOPE 0.2f
#define BN_EPS  1e-5f
#define EBLK 20
#define NBLK 49

typedef __attribute__((ext_vector_type(8))) short short8;
typedef __attribute__((ext_vector_type(4))) float f32x4;

__device__ __forceinline__ unsigned bf16rn(float f) {
    unsigned u = __float_as_uint(f);
    return (u + 0x7FFFu + ((u >> 16) & 1u)) >> 16;   // round-to-nearest-even
}
// unpack 4 bf16 (uint2) -> float4
__device__ __forceinline__ float4 unp4(uint2 p) {
    return make_float4(__uint_as_float(p.x << 16),
                       __uint_as_float(p.x & 0xFFFF0000u),
                       __uint_as_float(p.y << 16),
                       __uint_as_float(p.y & 0xFFFF0000u));
}

// ------------- W[k][n] f32 -> WT[n][k] bf16 -------------
__global__ void wt_kernel(const float* __restrict__ W, ushort* __restrict__ WT)
{
    int i = blockIdx.x * 256 + threadIdx.x;          // 65536
    int k = i >> 8, n = i & 255;
    WT[n * 256 + k] = (ushort)bf16rn(W[i]);
}

// ---------------- MFMA GEMM: 64x256 tile, 8 waves, full-width rows ----------------
// xwb (bf16) = A @ W ; fused s1/s2 attention dots with LDS reduce (no atomics)
#define BMM 64
#define BNN 256
#define BKK 64
__global__ __launch_bounds__(512) void gemm_mfma(
    const float* __restrict__ A, const ushort* __restrict__ WT,
    const float* __restrict__ att,
    ushort* __restrict__ xwb, float* __restrict__ s1, float* __restrict__ s2)
{
    __shared__ __align__(16) char lds[40960];
    char* As = lds;            // [64 rows][64 k] bf16, XOR-swizzled (8 KB)
    char* Bs = lds + 8192;     // [256 cols][64 k] bf16, XOR-swizzled (32 KB)
    float* sred = (float*)lds; // reused after compute: [8 waves][64 rows][2]
    int tid = threadIdx.x;
    int lane = tid & 63, w = tid >> 6;          // 8 waves
    int bm = blockIdx.x * BMM;
    f32x4 acc[4][2] = {};

    // staging coords (constant per thread)
    int arow0 = tid >> 4, ac4 = (tid & 15) * 4;   // A: rows arow0, arow0+32
    int bn0   = tid >> 3, bkc = (tid & 7) * 8;    // B: n = bn0 + 64*i

    float4 aReg[2];
    uint4  bReg[4];

    // prologue: load tile 0
    #pragma unroll
    for (int i = 0; i < 2; ++i) {
        int gr = bm + arow0 + 32 * i;
        aReg[i] = (gr < N_NODES) ? *(const float4*)(A + (size_t)gr * DIM + ac4)
                                 : make_float4(0.f, 0.f, 0.f, 0.f);
    }
    #pragma unroll
    for (int i = 0; i < 4; ++i)
        bReg[i] = *(const uint4*)(WT + (size_t)(bn0 + 64 * i) * DIM + bkc);

    #pragma unroll
    for (int t = 0; t < 4; ++t) {
        // write current regs -> LDS (f32->bf16 convert for A)
        #pragma unroll
        for (int i = 0; i < 2; ++i) {
            int row = arow0 + 32 * i;
            uint2 p;
            p.x = bf16rn(aReg[i].x) | (bf16rn(aReg[i].y) << 16);
            p.y = bf16rn(aReg[i].z) | (bf16rn(aReg[i].w) << 16);
            int off = row * 128 + ((ac4 * 2) ^ ((row & 7) << 4));
            *(uint2*)(As + off) = p;
        }
        #pragma unroll
        for (int i = 0; i < 4; ++i) {
            int n = bn0 + 64 * i;
            int off = n * 128 + ((bkc * 2) ^ ((n & 7) << 4));
            *(uint4*)(Bs + off) = bReg[i];
        }
        __syncthreads();
        // prefetch next tile into regs (overlaps the MFMA cluster below)
        if (t < 3) {
            int k0 = (t + 1) * BKK;
            #pragma unroll
            for (int i = 0; i < 2; ++i) {
                int gr = bm + arow0 + 32 * i;
                aReg[i] = (gr < N_NODES) ? *(const float4*)(A + (size_t)gr * DIM + k0 + ac4)
                                         : make_float4(0.f, 0.f, 0.f, 0.f);
            }
            #pragma unroll
            for (int i = 0; i < 4; ++i)
                bReg[i] = *(const uint4*)(WT + (size_t)(bn0 + 64 * i) * DIM + k0 + bkc);
        }
        // compute on LDS tile
        #pragma unroll
        for (int kk = 0; kk < 2; ++kk) {
            short8 a[4], b[2];
            int kb = (kk * 32 + (lane >> 4) * 8) * 2;
            #pragma unroll
            for (int m = 0; m < 4; ++m) {
                int row = m * 16 + (lane & 15);
                a[m] = *(const short8*)(As + row * 128 + (kb ^ ((row & 7) << 4)));
            }
            #pragma unroll
            for (int nf = 0; nf < 2; ++nf) {
                int col = w * 32 + nf * 16 + (lane & 15);
                b[nf] = *(const short8*)(Bs + col * 128 + (kb ^ ((col & 7) << 4)));
            }
            #pragma unroll
            for (int m = 0; m < 4; ++m)
                #pragma unroll
                for (int nf = 0; nf < 2; ++nf)
                    acc[m][nf] = __builtin_amdgcn_mfma_f32_16x16x32_bf16(
                        a[m], b[nf], acc[m][nf], 0, 0, 0);
        }
        __syncthreads();
    }

    // epilogue: bf16 stores + fused attention partial dots (LDS reduce)
    float att1v[2], att2v[2];
    #pragma unroll
    for (int nf = 0; nf < 2; ++nf) {
        int col = w * 32 + nf * 16 + (lane & 15);
        att1v[nf] = att[col];
        att2v[nf] = att[DIM + col];
    }
    #pragma unroll
    for (int m = 0; m < 4; ++m)
        #pragma unroll
        for (int r = 0; r < 4; ++r) {
            int lrow = m * 16 + (lane >> 4) * 4 + r;
            int row = bm + lrow;
            if (row < N_NODES) {
                #pragma unroll
                for (int nf = 0; nf < 2; ++nf) {
                    int col = w * 32 + nf * 16 + (lane & 15);
                    xwb[(size_t)row * DIM + col] = (ushort)bf16rn(acc[m][nf][r]);
                }
            }
            float p1 = acc[m][0][r] * att1v[0] + acc[m][1][r] * att1v[1];
            float p2 = acc[m][0][r] * att2v[0] + acc[m][1][r] * att2v[1];
            #pragma unroll
            for (int msk = 1; msk < 16; msk <<= 1) {
                p1 += __shfl_xor(p1, msk);
                p2 += __shfl_xor(p2, msk);
            }
            if ((lane & 15) == 0) {
                sred[(w * 64 + lrow) * 2 + 0] = p1;
                sred[(w * 64 + lrow) * 2 + 1] = p2;
            }
        }
    __syncthreads();
    if (tid < 64) {
        int row = bm + tid;
        if (row < N_NODES) {
            float v1 = 0.f, v2 = 0.f;
            #pragma unroll
            for (int wv = 0; wv < 8; ++wv) {
                v1 += sred[(wv * 64 + tid) * 2 + 0];
                v2 += sred[(wv * 64 + tid) * 2 + 1];
            }
            s1[row] = v1;
            s2[row] = v2;
        }
    }
}

// ------------- alpha: leaky + exp, esum + degree histograms -------------
__global__ void alpha_kernel(
    const int* __restrict__ node_idx, const int* __restrict__ edge_idx,
    const float* __restrict__ s1, const float* __restrict__ s2,
    float* __restrict__ ealpha, float* __restrict__ esum,
    int* __restrict__ cnt_n, int* __restrict__ cnt_e)
{
    int e = blockIdx.x * blockDim.x + threadIdx.x;
    if (e >= N_INC) return;
    int n = node_idx[e], h = edge_idx[e];
    float a = s1[n] + s2[h];
    a = a > 0.f ? a : NEG_SLOPE * a;
    float ea = __expf(a);                 // no max-subtraction: |a| <~ 12, safe in f32
    ealpha[e] = ea;
    atomicAdd(esum + n, ea);
    atomicAdd(cnt_n + n, 1);
    atomicAdd(cnt_e + h, 1);
}

// ------------- scan phase 1 -------------
__global__ __launch_bounds__(1024) void scan_partial(
    const int* __restrict__ cnt_e, int* __restrict__ start_e, int* __restrict__ totals_e,
    const int* __restrict__ cnt_n, int* __restrict__ start_n, int* __restrict__ totals_n)
{
    int b = blockIdx.x;
    const int* cnt; int* start; int* totals; int n; int cb;
    if (b < EBLK) { cnt = cnt_e; start = start_e; totals = totals_e; n = M_EDGES; cb = b; }
    else          { cnt = cnt_n; start = start_n; totals = totals_n; n = N_NODES; cb = b - EBLK; }
    int tid = threadIdx.x, lane = tid & 63, wid = tid >> 6;
    int i = cb * 1024 + tid;
    int v = (i < n) ? cnt[i] : 0;
    #pragma unroll
    for (int off = 1; off < 64; off <<= 1) {
        int t = __shfl_up(v, off);
        if (lane >= off) v += t;
    }
    __shared__ int wsum[16];
    if (lane == 63) wsum[wid] = v;
    __syncthreads();
    if (wid == 0 && lane < 16) {
        int s = wsum[lane];
        #pragma unroll
        for (int off = 1; off < 16; off <<= 1) {
            int t = __shfl_up(s, off);
            if (lane >= off) s += t;
        }
        wsum[lane] = s;
    }
    __syncthreads();
    if (wid > 0) v += wsum[wid - 1];
    if (i < n) start[i + 1] = v;
    if (tid == 1023) totals[cb] = v;
}

// ------------- scan phase 2 -------------
__global__ void scan_totals(
    const int* __restrict__ totals_e, int* __restrict__ boff_e,
    const int* __restrict__ totals_n, int* __restrict__ boff_n,
    int* __restrict__ start_e, int* __restrict__ start_n)
{
    int lane = threadIdx.x;
    int ve0 = (lane < EBLK) ? totals_e[lane] : 0;
    int ve = ve0;
    #pragma unroll
    for (int off = 1; off < 64; off <<= 1) {
        int t = __shfl_up(ve, off);
        if (lane >= off) ve += t;
    }
    if (lane < EBLK) boff_e[lane] = ve - ve0;
    int vn0 = (lane < NBLK) ? totals_n[lane] : 0;
    int vn = vn0;
    #pragma unroll
    for (int off = 1; off < 64; off <<= 1) {
        int t = __shfl_up(vn, off);
        if (lane >= off) vn += t;
    }
    if (lane < NBLK) boff_n[lane] = vn - vn0;
    if (lane == 0) { start_e[0] = 0; start_n[0] = 0; }
}

// ------------- scan phase 3 + cursor init + rnorm (fused) -------------
__global__ void scan_add(
    int* __restrict__ start_e, const int* __restrict__ boff_e,
    const int* __restrict__ cnt_e, int* __restrict__ cur_e,
    int* __restrict__ start_n, const int* __restrict__ boff_n,
    const int* __restrict__ cnt_n, int* __restrict__ cur_n,
    const float* __restrict__ esum, float* __restrict__ rnorm)
{
    int id = blockIdx.x * 256 + threadIdx.x;
    if (id < M_EDGES) {
        int s = start_e[id + 1] + boff_e[id >> 10];
        start_e[id + 1] = s;
        cur_e[id] = s - cnt_e[id];
    } else if (id < M_EDGES + N_NODES) {
        int j = id - M_EDGES;
        int s = start_n[j + 1] + boff_n[j >> 10];
        start_n[j + 1] = s;
        cur_n[j] = s - cnt_n[j];
        rnorm[j] = 1.f / (esum[j] + 1e-16f);
    }
}

// ------------- CSR scatter + normalized attention an[e] -------------
__global__ void scatter_kernel(
    const int* __restrict__ node_idx, const int* __restrict__ edge_idx,
    const float* __restrict__ ealpha, const float* __restrict__ rnorm,
    int* __restrict__ cur_e, int* __restrict__ cur_n,
    int* __restrict__ list_e, int* __restrict__ list_n, float* __restrict__ an)
{
    int e = blockIdx.x * blockDim.x + threadIdx.x;
    if (e >= N_INC) return;
    int n = node_idx[e];
    int p = atomicAdd(cur_e + edge_idx[e], 1);
    list_e[p] = e;
    int q = atomicAdd(cur_n + n, 1);
    list_n[q] = e;
    an[e] = ealpha[e] * rnorm[n];
}

// ------------- stage 1: gather bf16 xw per hyperedge -> bf16 edge_feat -------------
__global__ __launch_bounds__(256) void stage1_kernel(
    const ushort* __restrict__ xwb, const int* __restrict__ node_idx,
    const float* __restrict__ an, const int* __restrict__ start_e,
    const int* __restrict__ list_e, ushort* __restrict__ edge_feat)
{
    int h = blockIdx.x * 4 + (threadIdx.x >> 6);
    if (h >= M_EDGES) return;
    int lane = threadIdx.x & 63;
    int j0 = start_e[h], j1 = start_e[h + 1];
    float4 acc = make_float4(0.f, 0.f, 0.f, 0.f);
    float4 ac2 = make_float4(0.f, 0.f, 0.f, 0.f);
    for (int base = j0; base < j1; base += 64) {
        int cnt = min(64, j1 - base);
        float wv = 0.f; int nv = 0;
        if (lane < cnt) { int e = list_e[base + lane]; wv = an[e]; nv = node_idx[e]; }
        int jj = 0;
        for (; jj + 4 <= cnt; jj += 4) {
            float wg0 = __shfl(wv, jj);     int n0 = __shfl(nv, jj);
            float wg1 = __shfl(wv, jj + 1); int n1 = __shfl(nv, jj + 1);
            float wg2 = __shfl(wv, jj + 2); int n2 = __shfl(nv, jj + 2);
            float wg3 = __shfl(wv, jj + 3); int n3 = __shfl(nv, jj + 3);
            uint2 p0 = *(const uint2*)(xwb + (size_t)n0 * DIM + lane * 4);
            uint2 p1 = *(const uint2*)(xwb + (size_t)n1 * DIM + lane * 4);
            uint2 p2 = *(const uint2*)(xwb + (size_t)n2 * DIM + lane * 4);
            uint2 p3 = *(const uint2*)(xwb + (size_t)n3 * DIM + lane * 4);
            float4 v0 = unp4(p0), v1 = unp4(p1), v2 = unp4(p2), v3 = unp4(p3);
            acc.x += wg0 * v0.x + wg1 * v1.x;  ac2.x += wg2 * v2.x + wg3 * v3.x;
            acc.y += wg0 * v0.y + wg1 * v1.y;  ac2.y += wg2 * v2.y + wg3 * v3.y;
            acc.z += wg0 * v0.z + wg1 * v1.z;  ac2.z += wg2 * v2.z + wg3 * v3.z;
            acc.w += wg0 * v0.w + wg1 * v1.w;  ac2.w += wg2 * v2.w + wg3 * v3.w;
        }
        for (; jj < cnt; ++jj) {
            float wg = __shfl(wv, jj); int n0 = __shfl(nv, jj);
            float4 v = unp4(*(const uint2*)(xwb + (size_t)n0 * DIM + lane * 4));
            acc.x += wg * v.x; acc.y += wg * v.y;
            acc.z += wg * v.z; acc.w += wg * v.w;
        }
    }
    acc.x += ac2.x; acc.y += ac2.y; acc.z += ac2.z; acc.w += ac2.w;
    float binv = (j1 > j0) ? 1.f / (float)(j1 - j0) : 0.f;
    uint2 p;
    p.x = bf16rn(acc.x * binv) | (bf16rn(acc.y * binv) << 16);
    p.y = bf16rn(acc.z * binv) | (bf16rn(acc.w * binv) << 16);
    *(uint2*)(edge_feat + (size_t)h * DIM + lane * 4) = p;
}

// ------------- stage 2: gather bf16 edge_feat per node, + bias -> f32 out -------------
__global__ __launch_bounds__(256) void stage2_kernel(
    const ushort* __restrict__ edge_feat, const int* __restrict__ edge_idx,
    const float* __restrict__ an, const int* __restrict__ start_n,
    const int* __restrict__ list_n, const float* __restrict__ bias,
    float* __restrict__ out)
{
    int n = blockIdx.x * 4 + (threadIdx.x >> 6);
    if (n >= N_NODES) return;
    int lane = threadIdx.x & 63;
    int j0 = start_n[n], j1 = start_n[n + 1];
    float4 acc = make_float4(0.f, 0.f, 0.f, 0.f);
    float4 ac2 = make_float4(0.f, 0.f, 0.f, 0.f);
    for (int base = j0; base < j1; base += 64) {
        int cnt = min(64, j1 - base);
        float wv = 0.f; int hv = 0;
        if (lane < cnt) { int e = list_n[base + lane]; wv = an[e]; hv = edge_idx[e]; }
        int jj = 0;
        for (; jj + 4 <= cnt; jj += 4) {
            float wg0 = __shfl(wv, jj);     int h0 = __shfl(hv, jj);
            float wg1 = __shfl(wv, jj + 1); int h1 = __shfl(hv, jj + 1);
            float wg2 = __shfl(wv, jj + 2); int h2 = __shfl(hv, jj + 2);
            float wg3 = __shfl(wv, jj + 3); int h3 = __shfl(hv, jj + 3);
            uint2 p0 = *(const uint2*)(edge_feat + (size_t)h0 * DIM + lane * 4);
            uint2 p1 = *(const uint2*)(edge_feat + (size_t)h1 * DIM + lane * 4);
            uint2 p2 = *(const uint2*)(edge_feat + (size_t)h2 * DIM + lane * 4);
            uint2 p3 = *(const uint2*)(edge_feat + (size_t)h3 * DIM + lane * 4);
            float4 v0 = unp4(p0), v1 = unp4(p1), v2 = unp4(p2), v3 = unp4(p3);
            acc.x += wg0 * v0.x + wg1 * v1.x;  ac2.x += wg2 * v2.x + wg3 * v3.x;
            acc.y += wg0 * v0.y + wg1 * v1.y;  ac2.y += wg2 * v2.y + wg3 * v3.y;
            acc.z += wg0 * v0.z + wg1 * v1.z;  ac2.z += wg2 * v2.z + wg3 * v3.z;
            acc.w += wg0 * v0.w + wg1 * v1.w;  ac2.w += wg2 * v2.w + wg3 * v3.w;
        }
        for (; jj < cnt; ++jj) {
            float wg = __shfl(wv, jj); int h0 = __shfl(hv, jj);
            float4 v = unp4(*(const uint2*)(edge_feat + (size_t)h0 * DIM + lane * 4));
            acc.x += wg * v.x; acc.y += wg * v.y;
            acc.z += wg * v.z; acc.w += wg * v.w;
        }
    }
    acc.x += ac2.x; acc.y += ac2.y; acc.z += ac2.z; acc.w += ac2.w;
    float dinv = (j1 > j0) ? 1.f / (float)(j1 - j0) : 0.f;
    float4 b = *(const float4*)(bias + lane * 4);
    acc.x = fmaf(acc.x, dinv, b.x); acc.y = fmaf(acc.y, dinv, b.y);
    acc.z = fmaf(acc.z, dinv, b.z); acc.w = fmaf(acc.w, dinv, b.w);
    *(float4*)(out + (size_t)n * DIM + lane * 4) = acc;
}

// ------------- BN column stats: float4 + LDS cross-wave reduce -------------
__global__ __launch_bounds__(256) void stats_kernel(
    const float* __restrict__ out, float* __restrict__ stats)
{
    __shared__ float lsum[4][256], lsq[4][256];
    int tid = threadIdx.x, lane = tid & 63, w = tid >> 6;
    int c4 = lane * 4;
    int rows_per = (N_NODES + gridDim.x - 1) / gridDim.x;
    int r0 = blockIdx.x * rows_per;
    int r1 = min(r0 + rows_per, N_NODES);
    float4 s = make_float4(0.f, 0.f, 0.f, 0.f);
    float4 q = make_float4(0.f, 0.f, 0.f, 0.f);
    for (int r = r0 + w; r < r1; r += 4) {
        float4 v = *(const float4*)(out + (size_t)r * DIM + c4);
        s.x += v.x; s.y += v.y; s.z += v.z; s.w += v.w;
        q.x += v.x * v.x; q.y += v.y * v.y; q.z += v.z * v.z; q.w += v.w * v.w;
    }
    *(float4*)&lsum[w][c4] = s;
    *(float4*)&lsq[w][c4] = q;
    __syncthreads();
    if (w == 0) {
        #pragma unroll
        for (int i = 1; i < 4; ++i) {
            s.x += lsum[i][c4]; s.y += lsum[i][c4 + 1]; s.z += lsum[i][c4 + 2]; s.w += lsum[i][c4 + 3];
            q.x += lsq[i][c4];  q.y += lsq[i][c4 + 1];  q.z += lsq[i][c4 + 2];  q.w += lsq[i][c4 + 3];
        }
        atomicAdd(stats + c4 + 0, s.x); atomicAdd(stats + c4 + 1, s.y);
        atomicAdd(stats + c4 + 2, s.z); atomicAdd(stats + c4 + 3, s.w);
        atomicAdd(stats + DIM + c4 + 0, q.x); atomicAdd(stats + DIM + c4 + 1, q.y);
        atomicAdd(stats + DIM + c4 + 2, q.z); atomicAdd(stats + DIM + c4 + 3, q.w);
    }
}

// ------------- BN prep: per-column scale/shift -------------
__global__ void bnprep_kernel(
    const float* __restrict__ stats, const float* __restrict__ gamma,
    const float* __restrict__ beta, float* __restrict__ scale, float* __restrict__ shift)
{
    int c = threadIdx.x;
    float mu = stats[c] * (1.f / N_NODES);
    float var = stats[DIM + c] * (1.f / N_NODES) - mu * mu;
    float sc = gamma[c] * rsqrtf(var + BN_EPS);
    scale[c] = sc;
    shift[c] = beta[c] - mu * sc;
}

// ------------- BN apply + ELU, streaming float4 -------------
__global__ __launch_bounds__(256) void bn_kernel(
    float* __restrict__ out, const float* __restrict__ scale, const float* __restrict__ shift)
{
    int idx = blockIdx.x * 256 + threadIdx.x;       // N*DIM/4 threads
    int c4 = (idx & 63) * 4;
    float4 sc = *(const float4*)(scale + c4);
    float4 sh = *(const float4*)(shift + c4);
    float4 v = ((float4*)out)[idx];
    v.x = fmaf(v.x, sc.x, sh.x); v.y = fmaf(v.y, sc.y, sh.y);
    v.z = fmaf(v.z, sc.z, sh.z); v.w = fmaf(v.w, sc.w, sh.w);
    v.x = v.x > 0.f ? v.x : __expf(v.x) - 1.f;
    v.y = v.y > 0.f ? v.y : __expf(v.y) - 1.f;
    v.z = v.z > 0.f ? v.z : __expf(v.z) - 1.f;
    v.w = v.w > 0.f ? v.w : __expf(v.w) - 1.f;
    ((float4*)out)[idx] = v;
}

extern "C" void kernel_launch(void* const* d_in, const int* in_sizes, int n_in,
                              void* d_out, int out_size, void* d_ws, size_t ws_size,
                              hipStream_t stream)
{
    const float* x        = (const float*)d_in[0];
    const int*   node_idx = (const int*)d_in[1];
    const int*   edge_idx = (const int*)d_in[2];
    const float* W        = (const float*)d_in[4];
    const float* att      = (const float*)d_in[5];
    const float* bias     = (const float*)d_in[6];
    const float* gamma    = (const float*)d_in[7];
    const float* beta     = (const float*)d_in[8];
    float* out = (float*)d_out;
    ushort* xwb = (ushort*)d_out;     // bf16 xw in first 25.6 MB of d_out; overwritten by stage2

    ushort* edge_feat = (ushort*)d_ws;                          // M*DIM bf16
    // ---- zeroed block (contiguous) ----
    int*   cnt_e   = (int*)(edge_feat + (size_t)M_EDGES * DIM); // M
    int*   cnt_n   = cnt_e + M_EDGES;                           // N
    float* stats   = (float*)(cnt_n + N_NODES);                 // 2*DIM
    float* esum    = stats + 2 * DIM;                           // N
    // ---- not zeroed ----
    float* s1      = esum + N_NODES;                            // N
    float* s2      = s1 + N_NODES;                              // N
    float* ealpha  = s2 + N_NODES;                              // E
    float* an      = ealpha + N_INC;                            // E
    float* rnorm   = an + N_INC;                                // N
    int*   start_e = (int*)(rnorm + N_NODES);                   // M+1
    int*   start_n = start_e + M_EDGES + 1;                     // N+1
    int*   cur_e   = start_n + N_NODES + 1;                     // M
    int*   cur_n   = cur_e + M_EDGES;                           // N
    int*   list_e  = cur_n + N_NODES;                           // E
    int*   list_n  = list_e + N_INC;                            // E
    ushort* WT     = (ushort*)(list_n + N_INC);                 // 256*256 bf16
    int*   totals_e = (int*)(WT + 256 * 256);                   // EBLK
    int*   boff_e   = totals_e + EBLK;                          // EBLK
    int*   totals_n = boff_e + EBLK;                            // NBLK
    int*   boff_n   = totals_n + NBLK;                          // NBLK
    float* scale    = (float*)(boff_n + NBLK);                  // DIM
    float* shift    = scale + DIM;                              // DIM

    hipMemsetAsync(cnt_e, 0,
        (size_t)(M_EDGES + N_NODES + 2 * DIM + N_NODES) * 4, stream);

    wt_kernel<<<256, 256, 0, stream>>>(W, WT);
    gemm_mfma<<<(N_NODES + BMM - 1) / BMM, 512, 0, stream>>>(x, WT, att, xwb, s1, s2);
    alpha_kernel<<<(N_INC + 255) / 256, 256, 0, stream>>>(node_idx, edge_idx, s1, s2, ealpha, esum, cnt_n, cnt_e);
    scan_partial<<<EBLK + NBLK, 1024, 0, stream>>>(cnt_e, start_e, totals_e, cnt_n, start_n, totals_n);
    scan_totals<<<1, 64, 0, stream>>>(totals_e, boff_e, totals_n, boff_n, start_e, start_n);
    scan_add<<<(M_EDGES + N_NODES + 255) / 256, 256, 0, stream>>>(
        start_e, boff_e, cnt_e, cur_e, start_n, boff_n, cnt_n, cur_n, esum, rnorm);
    scatter_kernel<<<(N_INC + 255) / 256, 256, 0, stream>>>(node_idx, edge_idx, ealpha, rnorm, cur_e, cur_n, list_e, list_n, an);
    stage1_kernel<<<(M_EDGES + 3) / 4, 256, 0, stream>>>(xwb, node_idx, an, start_e, list_e, edge_feat);
    stage2_kernel<<<(N_NODES + 3) / 4, 256, 0, stream>>>(edge_feat, edge_idx, an, start_n, list_n, bias, out);
    stats_kernel<<<128, 256, 0, stream>>>(out, stats);
    bnprep_kernel<<<1, 256, 0, stream>>>(stats, gamma, beta, scale, shift);
    bn_kernel<<<N_NODES * DIM / 4 / 256, 256, 0, stream>>>(out, scale, shift);
}

// Round 9
// 236.202 us; speedup vs baseline: 1.1666x; 1.1666x over previous
//
#include <hip/hip_runtime.h>

#define N_NODES 50000
#define N_INC   300000
#define DIM     256
#define M_EDGES 20000
#define NEG_SLOPE 0.2f
#define BN_EPS  1e-5f
#define EBLK 20
#define NBLK 49

typedef __attribute__((ext_vector_type(8))) short short8;
typedef __attribute__((ext_vector_type(4))) float f32x4;

__device__ __forceinline__ unsigned bf16rn(float f) {
    unsigned u = __float_as_uint(f);
    return (u + 0x7FFFu + ((u >> 16) & 1u)) >> 16;   // round-to-nearest-even
}
// unpack 4 bf16 (uint2) -> float4
__device__ __forceinline__ float4 unp4(uint2 p) {
    return make_float4(__uint_as_float(p.x << 16),
                       __uint_as_float(p.x & 0xFFFF0000u),
                       __uint_as_float(p.y << 16),
                       __uint_as_float(p.y & 0xFFFF0000u));
}

// ------------- W[k][n] f32 -> WT[n][k] bf16 -------------
__global__ void wt_kernel(const float* __restrict__ W, ushort* __restrict__ WT)
{
    int i = blockIdx.x * 256 + threadIdx.x;          // 65536
    int k = i >> 8, n = i & 255;
    WT[n * 256 + k] = (ushort)bf16rn(W[i]);
}

// ---------------- persistent-W MFMA GEMM: whole WT (128 KB) in LDS ----------------
// 512 threads / 8 waves; wave owns 32 rows x all 256 cols; one barrier total.
// Fused s1/s2 attention dots complete in-wave (no atomics).
#define GBM 256   // rows per block (8 waves x 32)
__global__ __launch_bounds__(512) void gemm_persist(
    const float* __restrict__ A, const ushort* __restrict__ WT,
    const float* __restrict__ att,
    ushort* __restrict__ xwb, float* __restrict__ s1, float* __restrict__ s2)
{
    __shared__ __align__(16) char Bs[131072];   // [256 cols][256 k] bf16, XOR-swizzled
    int tid = threadIdx.x;
    int lane = tid & 63, w = tid >> 6;

    // stage whole WT: 8192 uint4
    #pragma unroll
    for (int i = 0; i < 16; ++i) {
        int flat = tid + 512 * i;
        int n = flat >> 5, kc = flat & 31;      // col, 16B-chunk
        uint4 v = *(const uint4*)(WT + n * 256 + kc * 8);
        int off = n * 512 + ((kc * 16) ^ ((n & 7) << 4));
        *(uint4*)(Bs + off) = v;
    }
    __syncthreads();

    int row0 = blockIdx.x * GBM + w * 32;       // wave's 32 rows (2 strips of 16)

    // A fragments: 2 strips x 8 k-chunks, direct global->reg->bf16
    short8 afrag[2][8];
    #pragma unroll
    for (int j = 0; j < 8; ++j) {
        #pragma unroll
        for (int s = 0; s < 2; ++s) {
            int row = row0 + s * 16 + (lane & 15);
            float4 u0 = make_float4(0.f, 0.f, 0.f, 0.f), u1 = u0;
            if (row < N_NODES) {
                const float* p = A + (size_t)row * DIM + j * 32 + (lane >> 4) * 8;
                u0 = *(const float4*)p;
                u1 = *(const float4*)(p + 4);
            }
            uint4 q;
            q.x = bf16rn(u0.x) | (bf16rn(u0.y) << 16);
            q.y = bf16rn(u0.z) | (bf16rn(u0.w) << 16);
            q.z = bf16rn(u1.x) | (bf16rn(u1.y) << 16);
            q.w = bf16rn(u1.z) | (bf16rn(u1.w) << 16);
            afrag[s][j] = *(short8*)&q;
        }
    }

    float p1a[2][4] = {}, p2a[2][4] = {};
    #pragma unroll
    for (int ch = 0; ch < 2; ++ch) {            // column halves (reg pressure)
        f32x4 acc[2][8] = {};
        #pragma unroll
        for (int j = 0; j < 8; ++j) {
            int kb = j * 64 + (lane >> 4) * 16;
            #pragma unroll
            for (int c = 0; c < 8; ++c) {
                int col = ch * 128 + c * 16 + (lane & 15);
                short8 b = *(const short8*)(Bs + col * 512 + (kb ^ ((col & 7) << 4)));
                acc[0][c] = __builtin_amdgcn_mfma_f32_16x16x32_bf16(afrag[0][j], b, acc[0][c], 0, 0, 0);
                acc[1][c] = __builtin_amdgcn_mfma_f32_16x16x32_bf16(afrag[1][j], b, acc[1][c], 0, 0, 0);
            }
        }
        // epilogue for this half: bf16 stores + dot partials
        #pragma unroll
        for (int c = 0; c < 8; ++c) {
            int col = ch * 128 + c * 16 + (lane & 15);
            float a1 = att[col], a2 = att[DIM + col];
            #pragma unroll
            for (int s = 0; s < 2; ++s)
                #pragma unroll
                for (int r = 0; r < 4; ++r) {
                    int row = row0 + s * 16 + (lane >> 4) * 4 + r;
                    float v = acc[s][c][r];
                    if (row < N_NODES)
                        xwb[(size_t)row * DIM + col] = (ushort)bf16rn(v);
                    p1a[s][r] += v * a1;
                    p2a[s][r] += v * a2;
                }
        }
    }
    // in-wave 16-lane reduce of full-row dots, plain stores
    #pragma unroll
    for (int s = 0; s < 2; ++s)
        #pragma unroll
        for (int r = 0; r < 4; ++r) {
            float p1 = p1a[s][r], p2 = p2a[s][r];
            #pragma unroll
            for (int msk = 1; msk < 16; msk <<= 1) {
                p1 += __shfl_xor(p1, msk);
                p2 += __shfl_xor(p2, msk);
            }
            int row = row0 + s * 16 + (lane >> 4) * 4 + r;
            if ((lane & 15) == 0 && row < N_NODES) {
                s1[row] = p1;
                s2[row] = p2;
            }
        }
}

// ------------- alpha: leaky + exp, esum + degree histograms -------------
__global__ void alpha_kernel(
    const int* __restrict__ node_idx, const int* __restrict__ edge_idx,
    const float* __restrict__ s1, const float* __restrict__ s2,
    float* __restrict__ ealpha, float* __restrict__ esum,
    int* __restrict__ cnt_n, int* __restrict__ cnt_e)
{
    int e = blockIdx.x * blockDim.x + threadIdx.x;
    if (e >= N_INC) return;
    int n = node_idx[e], h = edge_idx[e];
    float a = s1[n] + s2[h];
    a = a > 0.f ? a : NEG_SLOPE * a;
    float ea = __expf(a);                 // no max-subtraction: |a| <~ 12, safe in f32
    ealpha[e] = ea;
    atomicAdd(esum + n, ea);
    atomicAdd(cnt_n + n, 1);
    atomicAdd(cnt_e + h, 1);
}

// ------------- scan phase 1 -------------
__global__ __launch_bounds__(1024) void scan_partial(
    const int* __restrict__ cnt_e, int* __restrict__ start_e, int* __restrict__ totals_e,
    const int* __restrict__ cnt_n, int* __restrict__ start_n, int* __restrict__ totals_n)
{
    int b = blockIdx.x;
    const int* cnt; int* start; int* totals; int n; int cb;
    if (b < EBLK) { cnt = cnt_e; start = start_e; totals = totals_e; n = M_EDGES; cb = b; }
    else          { cnt = cnt_n; start = start_n; totals = totals_n; n = N_NODES; cb = b - EBLK; }
    int tid = threadIdx.x, lane = tid & 63, wid = tid >> 6;
    int i = cb * 1024 + tid;
    int v = (i < n) ? cnt[i] : 0;
    #pragma unroll
    for (int off = 1; off < 64; off <<= 1) {
        int t = __shfl_up(v, off);
        if (lane >= off) v += t;
    }
    __shared__ int wsum[16];
    if (lane == 63) wsum[wid] = v;
    __syncthreads();
    if (wid == 0 && lane < 16) {
        int s = wsum[lane];
        #pragma unroll
        for (int off = 1; off < 16; off <<= 1) {
            int t = __shfl_up(s, off);
            if (lane >= off) s += t;
        }
        wsum[lane] = s;
    }
    __syncthreads();
    if (wid > 0) v += wsum[wid - 1];
    if (i < n) start[i + 1] = v;
    if (tid == 1023) totals[cb] = v;
}

// ------------- scan phase 2 -------------
__global__ void scan_totals(
    const int* __restrict__ totals_e, int* __restrict__ boff_e,
    const int* __restrict__ totals_n, int* __restrict__ boff_n,
    int* __restrict__ start_e, int* __restrict__ start_n)
{
    int lane = threadIdx.x;
    int ve0 = (lane < EBLK) ? totals_e[lane] : 0;
    int ve = ve0;
    #pragma unroll
    for (int off = 1; off < 64; off <<= 1) {
        int t = __shfl_up(ve, off);
        if (lane >= off) ve += t;
    }
    if (lane < EBLK) boff_e[lane] = ve - ve0;
    int vn0 = (lane < NBLK) ? totals_n[lane] : 0;
    int vn = vn0;
    #pragma unroll
    for (int off = 1; off < 64; off <<= 1) {
        int t = __shfl_up(vn, off);
        if (lane >= off) vn += t;
    }
    if (lane < NBLK) boff_n[lane] = vn - vn0;
    if (lane == 0) { start_e[0] = 0; start_n[0] = 0; }
}

// ------------- scan phase 3 + cursor init + rnorm (fused) -------------
__global__ void scan_add(
    int* __restrict__ start_e, const int* __restrict__ boff_e,
    const int* __restrict__ cnt_e, int* __restrict__ cur_e,
    int* __restrict__ start_n, const int* __restrict__ boff_n,
    const int* __restrict__ cnt_n, int* __restrict__ cur_n,
    const float* __restrict__ esum, float* __restrict__ rnorm)
{
    int id = blockIdx.x * 256 + threadIdx.x;
    if (id < M_EDGES) {
        int s = start_e[id + 1] + boff_e[id >> 10];
        start_e[id + 1] = s;
        cur_e[id] = s - cnt_e[id];
    } else if (id < M_EDGES + N_NODES) {
        int j = id - M_EDGES;
        int s = start_n[j + 1] + boff_n[j >> 10];
        start_n[j + 1] = s;
        cur_n[j] = s - cnt_n[j];
        rnorm[j] = 1.f / (esum[j] + 1e-16f);
    }
}

// ------------- CSR scatter + normalized attention an[e] -------------
__global__ void scatter_kernel(
    const int* __restrict__ node_idx, const int* __restrict__ edge_idx,
    const float* __restrict__ ealpha, const float* __restrict__ rnorm,
    int* __restrict__ cur_e, int* __restrict__ cur_n,
    int* __restrict__ list_e, int* __restrict__ list_n, float* __restrict__ an)
{
    int e = blockIdx.x * blockDim.x + threadIdx.x;
    if (e >= N_INC) return;
    int n = node_idx[e];
    int p = atomicAdd(cur_e + edge_idx[e], 1);
    list_e[p] = e;
    int q = atomicAdd(cur_n + n, 1);
    list_n[q] = e;
    an[e] = ealpha[e] * rnorm[n];
}

// ------------- stage 1: gather bf16 xw per hyperedge -> bf16 edge_feat -------------
__global__ __launch_bounds__(256) void stage1_kernel(
    const ushort* __restrict__ xwb, const int* __restrict__ node_idx,
    const float* __restrict__ an, const int* __restrict__ start_e,
    const int* __restrict__ list_e, ushort* __restrict__ edge_feat)
{
    int h = blockIdx.x * 4 + (threadIdx.x >> 6);
    if (h >= M_EDGES) return;
    int lane = threadIdx.x & 63;
    int j0 = start_e[h], j1 = start_e[h + 1];
    float4 acc = make_float4(0.f, 0.f, 0.f, 0.f);
    float4 ac2 = make_float4(0.f, 0.f, 0.f, 0.f);
    for (int base = j0; base < j1; base += 64) {
        int cnt = min(64, j1 - base);
        float wv = 0.f; int nv = 0;
        if (lane < cnt) { int e = list_e[base + lane]; wv = an[e]; nv = node_idx[e]; }
        int jj = 0;
        for (; jj + 4 <= cnt; jj += 4) {
            float wg0 = __shfl(wv, jj);     int n0 = __shfl(nv, jj);
            float wg1 = __shfl(wv, jj + 1); int n1 = __shfl(nv, jj + 1);
            float wg2 = __shfl(wv, jj + 2); int n2 = __shfl(nv, jj + 2);
            float wg3 = __shfl(wv, jj + 3); int n3 = __shfl(nv, jj + 3);
            uint2 p0 = *(const uint2*)(xwb + (size_t)n0 * DIM + lane * 4);
            uint2 p1 = *(const uint2*)(xwb + (size_t)n1 * DIM + lane * 4);
            uint2 p2 = *(const uint2*)(xwb + (size_t)n2 * DIM + lane * 4);
            uint2 p3 = *(const uint2*)(xwb + (size_t)n3 * DIM + lane * 4);
            float4 v0 = unp4(p0), v1 = unp4(p1), v2 = unp4(p2), v3 = unp4(p3);
            acc.x += wg0 * v0.x + wg1 * v1.x;  ac2.x += wg2 * v2.x + wg3 * v3.x;
            acc.y += wg0 * v0.y + wg1 * v1.y;  ac2.y += wg2 * v2.y + wg3 * v3.y;
            acc.z += wg0 * v0.z + wg1 * v1.z;  ac2.z += wg2 * v2.z + wg3 * v3.z;
            acc.w += wg0 * v0.w + wg1 * v1.w;  ac2.w += wg2 * v2.w + wg3 * v3.w;
        }
        for (; jj < cnt; ++jj) {
            float wg = __shfl(wv, jj); int n0 = __shfl(nv, jj);
            float4 v = unp4(*(const uint2*)(xwb + (size_t)n0 * DIM + lane * 4));
            acc.x += wg * v.x; acc.y += wg * v.y;
            acc.z += wg * v.z; acc.w += wg * v.w;
        }
    }
    acc.x += ac2.x; acc.y += ac2.y; acc.z += ac2.z; acc.w += ac2.w;
    float binv = (j1 > j0) ? 1.f / (float)(j1 - j0) : 0.f;
    uint2 p;
    p.x = bf16rn(acc.x * binv) | (bf16rn(acc.y * binv) << 16);
    p.y = bf16rn(acc.z * binv) | (bf16rn(acc.w * binv) << 16);
    *(uint2*)(edge_feat + (size_t)h * DIM + lane * 4) = p;
}

// ------------- stage 2: gather bf16 edge_feat per node, + bias -> f32 out -------------
__global__ __launch_bounds__(256) void stage2_kernel(
    const ushort* __restrict__ edge_feat, const int* __restrict__ edge_idx,
    const float* __restrict__ an, const int* __restrict__ start_n,
    const int* __restrict__ list_n, const float* __restrict__ bias,
    float* __restrict__ out)
{
    int n = blockIdx.x * 4 + (threadIdx.x >> 6);
    if (n >= N_NODES) return;
    int lane = threadIdx.x & 63;
    int j0 = start_n[n], j1 = start_n[n + 1];
    float4 acc = make_float4(0.f, 0.f, 0.f, 0.f);
    float4 ac2 = make_float4(0.f, 0.f, 0.f, 0.f);
    for (int base = j0; base < j1; base += 64) {
        int cnt = min(64, j1 - base);
        float wv = 0.f; int hv = 0;
        if (lane < cnt) { int e = list_n[base + lane]; wv = an[e]; hv = edge_idx[e]; }
        int jj = 0;
        for (; jj + 4 <= cnt; jj += 4) {
            float wg0 = __shfl(wv, jj);     int h0 = __shfl(hv, jj);
            float wg1 = __shfl(wv, jj + 1); int h1 = __shfl(hv, jj + 1);
            float wg2 = __shfl(wv, jj + 2); int h2 = __shfl(hv, jj + 2);
            float wg3 = __shfl(wv, jj + 3); int h3 = __shfl(hv, jj + 3);
            uint2 p0 = *(const uint2*)(edge_feat + (size_t)h0 * DIM + lane * 4);
            uint2 p1 = *(const uint2*)(edge_feat + (size_t)h1 * DIM + lane * 4);
            uint2 p2 = *(const uint2*)(edge_feat + (size_t)h2 * DIM + lane * 4);
            uint2 p3 = *(const uint2*)(edge_feat + (size_t)h3 * DIM + lane * 4);
            float4 v0 = unp4(p0), v1 = unp4(p1), v2 = unp4(p2), v3 = unp4(p3);
            acc.x += wg0 * v0.x + wg1 * v1.x;  ac2.x += wg2 * v2.x + wg3 * v3.x;
            acc.y += wg0 * v0.y + wg1 * v1.y;  ac2.y += wg2 * v2.y + wg3 * v3.y;
            acc.z += wg0 * v0.z + wg1 * v1.z;  ac2.z += wg2 * v2.z + wg3 * v3.z;
            acc.w += wg0 * v0.w + wg1 * v1.w;  ac2.w += wg2 * v2.w + wg3 * v3.w;
        }
        for (; jj < cnt; ++jj) {
            float wg = __shfl(wv, jj); int h0 = __shfl(hv, jj);
            float4 v = unp4(*(const uint2*)(edge_feat + (size_t)h0 * DIM + lane * 4));
            acc.x += wg * v.x; acc.y += wg * v.y;
            acc.z += wg * v.z; acc.w += wg * v.w;
        }
    }
    acc.x += ac2.x; acc.y += ac2.y; acc.z += ac2.z; acc.w += ac2.w;
    float dinv = (j1 > j0) ? 1.f / (float)(j1 - j0) : 0.f;
    float4 b = *(const float4*)(bias + lane * 4);
    acc.x = fmaf(acc.x, dinv, b.x); acc.y = fmaf(acc.y, dinv, b.y);
    acc.z = fmaf(acc.z, dinv, b.z); acc.w = fmaf(acc.w, dinv, b.w);
    *(float4*)(out + (size_t)n * DIM + lane * 4) = acc;
}

// ------------- BN column stats: float4 + LDS cross-wave reduce -------------
__global__ __launch_bounds__(256) void stats_kernel(
    const float* __restrict__ out, float* __restrict__ stats)
{
    __shared__ float lsum[4][256], lsq[4][256];
    int tid = threadIdx.x, lane = tid & 63, w = tid >> 6;
    int c4 = lane * 4;
    int rows_per = (N_NODES + gridDim.x - 1) / gridDim.x;
    int r0 = blockIdx.x * rows_per;
    int r1 = min(r0 + rows_per, N_NODES);
    float4 s = make_float4(0.f, 0.f, 0.f, 0.f);
    float4 q = make_float4(0.f, 0.f, 0.f, 0.f);
    for (int r = r0 + w; r < r1; r += 4) {
        float4 v = *(const float4*)(out + (size_t)r * DIM + c4);
        s.x += v.x; s.y += v.y; s.z += v.z; s.w += v.w;
        q.x += v.x * v.x; q.y += v.y * v.y; q.z += v.z * v.z; q.w += v.w * v.w;
    }
    *(float4*)&lsum[w][c4] = s;
    *(float4*)&lsq[w][c4] = q;
    __syncthreads();
    if (w == 0) {
        #pragma unroll
        for (int i = 1; i < 4; ++i) {
            s.x += lsum[i][c4]; s.y += lsum[i][c4 + 1]; s.z += lsum[i][c4 + 2]; s.w += lsum[i][c4 + 3];
            q.x += lsq[i][c4];  q.y += lsq[i][c4 + 1];  q.z += lsq[i][c4 + 2];  q.w += lsq[i][c4 + 3];
        }
        atomicAdd(stats + c4 + 0, s.x); atomicAdd(stats + c4 + 1, s.y);
        atomicAdd(stats + c4 + 2, s.z); atomicAdd(stats + c4 + 3, s.w);
        atomicAdd(stats + DIM + c4 + 0, q.x); atomicAdd(stats + DIM + c4 + 1, q.y);
        atomicAdd(stats + DIM + c4 + 2, q.z); atomicAdd(stats + DIM + c4 + 3, q.w);
    }
}

// ------------- BN prep: per-column scale/shift -------------
__global__ void bnprep_kernel(
    const float* __restrict__ stats, const float* __restrict__ gamma,
    const float* __restrict__ beta, float* __restrict__ scale, float* __restrict__ shift)
{
    int c = threadIdx.x;
    float mu = stats[c] * (1.f / N_NODES);
    float var = stats[DIM + c] * (1.f / N_NODES) - mu * mu;
    float sc = gamma[c] * rsqrtf(var + BN_EPS);
    scale[c] = sc;
    shift[c] = beta[c] - mu * sc;
}

// ------------- BN apply + ELU, streaming float4 -------------
__global__ __launch_bounds__(256) void bn_kernel(
    float* __restrict__ out, const float* __restrict__ scale, const float* __restrict__ shift)
{
    int idx = blockIdx.x * 256 + threadIdx.x;       // N*DIM/4 threads
    int c4 = (idx & 63) * 4;
    float4 sc = *(const float4*)(scale + c4);
    float4 sh = *(const float4*)(shift + c4);
    float4 v = ((float4*)out)[idx];
    v.x = fmaf(v.x, sc.x, sh.x); v.y = fmaf(v.y, sc.y, sh.y);
    v.z = fmaf(v.z, sc.z, sh.z); v.w = fmaf(v.w, sc.w, sh.w);
    v.x = v.x > 0.f ? v.x : __expf(v.x) - 1.f;
    v.y = v.y > 0.f ? v.y : __expf(v.y) - 1.f;
    v.z = v.z > 0.f ? v.z : __expf(v.z) - 1.f;
    v.w = v.w > 0.f ? v.w : __expf(v.w) - 1.f;
    ((float4*)out)[idx] = v;
}

extern "C" void kernel_launch(void* const* d_in, const int* in_sizes, int n_in,
                              void* d_out, int out_size, void* d_ws, size_t ws_size,
                              hipStream_t stream)
{
    const float* x        = (const float*)d_in[0];
    const int*   node_idx = (const int*)d_in[1];
    const int*   edge_idx = (const int*)d_in[2];
    const float* W        = (const float*)d_in[4];
    const float* att      = (const float*)d_in[5];
    const float* bias     = (const float*)d_in[6];
    const float* gamma    = (const float*)d_in[7];
    const float* beta     = (const float*)d_in[8];
    float* out = (float*)d_out;
    ushort* xwb = (ushort*)d_out;     // bf16 xw in first 25.6 MB of d_out; overwritten by stage2

    ushort* edge_feat = (ushort*)d_ws;                          // M*DIM bf16
    // ---- zeroed block (contiguous) ----
    int*   cnt_e   = (int*)(edge_feat + (size_t)M_EDGES * DIM); // M
    int*   cnt_n   = cnt_e + M_EDGES;                           // N
    float* stats   = (float*)(cnt_n + N_NODES);                 // 2*DIM
    float* esum    = stats + 2 * DIM;                           // N
    // ---- not zeroed ----
    float* s1      = esum + N_NODES;                            // N
    float* s2      = s1 + N_NODES;                              // N
    float* ealpha  = s2 + N_NODES;                              // E
    float* an      = ealpha + N_INC;                            // E
    float* rnorm   = an + N_INC;                                // N
    int*   start_e = (int*)(rnorm + N_NODES);                   // M+1
    int*   start_n = start_e + M_EDGES + 1;                     // N+1
    int*   cur_e   = start_n + N_NODES + 1;                     // M
    int*   cur_n   = cur_e + M_EDGES;                           // N
    int*   list_e  = cur_n + N_NODES;                           // E
    int*   list_n  = list_e + N_INC;                            // E
    ushort* WT     = (ushort*)(list_n + N_INC);                 // 256*256 bf16
    int*   totals_e = (int*)(WT + 256 * 256);                   // EBLK
    int*   boff_e   = totals_e + EBLK;                          // EBLK
    int*   totals_n = boff_e + EBLK;                            // NBLK
    int*   boff_n   = totals_n + NBLK;                          // NBLK
    float* scale    = (float*)(boff_n + NBLK);                  // DIM
    float* shift    = scale + DIM;                              // DIM

    hipMemsetAsync(cnt_e, 0,
        (size_t)(M_EDGES + N_NODES + 2 * DIM + N_NODES) * 4, stream);

    wt_kernel<<<256, 256, 0, stream>>>(W, WT);
    gemm_persist<<<(N_NODES + GBM - 1) / GBM, 512, 0, stream>>>(x, WT, att, xwb, s1, s2);
    alpha_kernel<<<(N_INC + 255) / 256, 256, 0, stream>>>(node_idx, edge_idx, s1, s2, ealpha, esum, cnt_n, cnt_e);
    scan_partial<<<EBLK + NBLK, 1024, 0, stream>>>(cnt_e, start_e, totals_e, cnt_n, start_n, totals_n);
    scan_totals<<<1, 64, 0, stream>>>(totals_e, boff_e, totals_n, boff_n, start_e, start_n);
    scan_add<<<(M_EDGES + N_NODES + 255) / 256, 256, 0, stream>>>(
        start_e, boff_e, cnt_e, cur_e, start_n, boff_n, cnt_n, cur_n, esum, rnorm);
    scatter_kernel<<<(N_INC + 255) / 256, 256, 0, stream>>>(node_idx, edge_idx, ealpha, rnorm, cur_e, cur_n, list_e, list_n, an);
    stage1_kernel<<<(M_EDGES + 3) / 4, 256, 0, stream>>>(xwb, node_idx, an, start_e, list_e, edge_feat);
    stage2_kernel<<<(N_NODES + 3) / 4, 256, 0, stream>>>(edge_feat, edge_idx, an, start_n, list_n, bias, out);
    stats_kernel<<<128, 256, 0, stream>>>(out, stats);
    bnprep_kernel<<<1, 256, 0, stream>>>(stats, gamma, beta, scale, shift);
    bn_kernel<<<N_NODES * DIM / 4 / 256, 256, 0, stream>>>(out, scale, shift);
}

// Round 10
// 207.388 us; speedup vs baseline: 1.3287x; 1.1389x over previous
//
#include <hip/hip_runtime.h>

#define N_NODES 50000
#define N_INC   300000
#define DIM     256
#define M_EDGES 20000
#define NEG_SLOPE 0.2f
#define BN_EPS  1e-5f
#define EBLK 20
#define NBLK 49

typedef __attribute__((ext_vector_type(8))) short short8;
typedef __attribute__((ext_vector_type(4))) float f32x4;

__device__ __forceinline__ unsigned bf16rn(float f) {
    unsigned u = __float_as_uint(f);
    return (u + 0x7FFFu + ((u >> 16) & 1u)) >> 16;   // round-to-nearest-even
}
// unpack 4 bf16 (uint2) -> float4
__device__ __forceinline__ float4 unp4(uint2 p) {
    return make_float4(__uint_as_float(p.x << 16),
                       __uint_as_float(p.x & 0xFFFF0000u),
                       __uint_as_float(p.y << 16),
                       __uint_as_float(p.y & 0xFFFF0000u));
}

// ------------- W[k][n] f32 -> WT[n][k] bf16 -------------
__global__ void wt_kernel(const float* __restrict__ W, ushort* __restrict__ WT)
{
    int i = blockIdx.x * 256 + threadIdx.x;          // 65536
    int k = i >> 8, n = i & 255;
    WT[n * 256 + k] = (ushort)bf16rn(W[i]);
}

// ---------------- persistent-W MFMA GEMM: whole WT (128 KB) in LDS ----------------
#define GBM 256   // rows per block (8 waves x 32)
__global__ __launch_bounds__(512) void gemm_persist(
    const float* __restrict__ A, const ushort* __restrict__ WT,
    const float* __restrict__ att,
    ushort* __restrict__ xwb, float* __restrict__ s1, float* __restrict__ s2)
{
    __shared__ __align__(16) char Bs[131072];   // [256 cols][256 k] bf16, XOR-swizzled
    int tid = threadIdx.x;
    int lane = tid & 63, w = tid >> 6;

    #pragma unroll
    for (int i = 0; i < 16; ++i) {
        int flat = tid + 512 * i;
        int n = flat >> 5, kc = flat & 31;
        uint4 v = *(const uint4*)(WT + n * 256 + kc * 8);
        int off = n * 512 + ((kc * 16) ^ ((n & 7) << 4));
        *(uint4*)(Bs + off) = v;
    }
    __syncthreads();

    int row0 = blockIdx.x * GBM + w * 32;

    short8 afrag[2][8];
    #pragma unroll
    for (int j = 0; j < 8; ++j) {
        #pragma unroll
        for (int s = 0; s < 2; ++s) {
            int row = row0 + s * 16 + (lane & 15);
            float4 u0 = make_float4(0.f, 0.f, 0.f, 0.f), u1 = u0;
            if (row < N_NODES) {
                const float* p = A + (size_t)row * DIM + j * 32 + (lane >> 4) * 8;
                u0 = *(const float4*)p;
                u1 = *(const float4*)(p + 4);
            }
            uint4 q;
            q.x = bf16rn(u0.x) | (bf16rn(u0.y) << 16);
            q.y = bf16rn(u0.z) | (bf16rn(u0.w) << 16);
            q.z = bf16rn(u1.x) | (bf16rn(u1.y) << 16);
            q.w = bf16rn(u1.z) | (bf16rn(u1.w) << 16);
            afrag[s][j] = *(short8*)&q;
        }
    }

    float p1a[2][4] = {}, p2a[2][4] = {};
    #pragma unroll
    for (int ch = 0; ch < 2; ++ch) {
        f32x4 acc[2][8] = {};
        #pragma unroll
        for (int j = 0; j < 8; ++j) {
            int kb = j * 64 + (lane >> 4) * 16;
            #pragma unroll
            for (int c = 0; c < 8; ++c) {
                int col = ch * 128 + c * 16 + (lane & 15);
                short8 b = *(const short8*)(Bs + col * 512 + (kb ^ ((col & 7) << 4)));
                acc[0][c] = __builtin_amdgcn_mfma_f32_16x16x32_bf16(afrag[0][j], b, acc[0][c], 0, 0, 0);
                acc[1][c] = __builtin_amdgcn_mfma_f32_16x16x32_bf16(afrag[1][j], b, acc[1][c], 0, 0, 0);
            }
        }
        #pragma unroll
        for (int c = 0; c < 8; ++c) {
            int col = ch * 128 + c * 16 + (lane & 15);
            float a1 = att[col], a2 = att[DIM + col];
            #pragma unroll
            for (int s = 0; s < 2; ++s)
                #pragma unroll
                for (int r = 0; r < 4; ++r) {
                    int row = row0 + s * 16 + (lane >> 4) * 4 + r;
                    float v = acc[s][c][r];
                    if (row < N_NODES)
                        xwb[(size_t)row * DIM + col] = (ushort)bf16rn(v);
                    p1a[s][r] += v * a1;
                    p2a[s][r] += v * a2;
                }
        }
    }
    #pragma unroll
    for (int s = 0; s < 2; ++s)
        #pragma unroll
        for (int r = 0; r < 4; ++r) {
            float p1 = p1a[s][r], p2 = p2a[s][r];
            #pragma unroll
            for (int msk = 1; msk < 16; msk <<= 1) {
                p1 += __shfl_xor(p1, msk);
                p2 += __shfl_xor(p2, msk);
            }
            int row = row0 + s * 16 + (lane >> 4) * 4 + r;
            if ((lane & 15) == 0 && row < N_NODES) {
                s1[row] = p1;
                s2[row] = p2;
            }
        }
}

// ------------- rank: ealpha + histogram-with-rank (2 atomics, no f32 atomic) -------------
__global__ void rank_kernel(
    const int* __restrict__ node_idx, const int* __restrict__ edge_idx,
    const float* __restrict__ s1, const float* __restrict__ s2,
    float* __restrict__ ealpha, unsigned* __restrict__ rank_pk,
    int* __restrict__ cnt_n, int* __restrict__ cnt_e)
{
    int e = blockIdx.x * blockDim.x + threadIdx.x;
    if (e >= N_INC) return;
    int n = node_idx[e], h = edge_idx[e];
    float a = s1[n] + s2[h];
    a = a > 0.f ? a : NEG_SLOPE * a;
    ealpha[e] = __expf(a);                // no max-subtraction: |a| small, safe in f32
    unsigned rn = (unsigned)atomicAdd(cnt_n + n, 1);
    unsigned re = (unsigned)atomicAdd(cnt_e + h, 1);
    rank_pk[e] = (re << 16) | rn;
}

// ------------- scan phase 1 -------------
__global__ __launch_bounds__(1024) void scan_partial(
    const int* __restrict__ cnt_e, int* __restrict__ start_e, int* __restrict__ totals_e,
    const int* __restrict__ cnt_n, int* __restrict__ start_n, int* __restrict__ totals_n)
{
    int b = blockIdx.x;
    const int* cnt; int* start; int* totals; int n; int cb;
    if (b < EBLK) { cnt = cnt_e; start = start_e; totals = totals_e; n = M_EDGES; cb = b; }
    else          { cnt = cnt_n; start = start_n; totals = totals_n; n = N_NODES; cb = b - EBLK; }
    int tid = threadIdx.x, lane = tid & 63, wid = tid >> 6;
    int i = cb * 1024 + tid;
    int v = (i < n) ? cnt[i] : 0;
    #pragma unroll
    for (int off = 1; off < 64; off <<= 1) {
        int t = __shfl_up(v, off);
        if (lane >= off) v += t;
    }
    __shared__ int wsum[16];
    if (lane == 63) wsum[wid] = v;
    __syncthreads();
    if (wid == 0 && lane < 16) {
        int s = wsum[lane];
        #pragma unroll
        for (int off = 1; off < 16; off <<= 1) {
            int t = __shfl_up(s, off);
            if (lane >= off) s += t;
        }
        wsum[lane] = s;
    }
    __syncthreads();
    if (wid > 0) v += wsum[wid - 1];
    if (i < n) start[i + 1] = v;
    if (tid == 1023) totals[cb] = v;
}

// ------------- scan phase 2 -------------
__global__ void scan_totals(
    const int* __restrict__ totals_e, int* __restrict__ boff_e,
    const int* __restrict__ totals_n, int* __restrict__ boff_n,
    int* __restrict__ start_e, int* __restrict__ start_n)
{
    int lane = threadIdx.x;
    int ve0 = (lane < EBLK) ? totals_e[lane] : 0;
    int ve = ve0;
    #pragma unroll
    for (int off = 1; off < 64; off <<= 1) {
        int t = __shfl_up(ve, off);
        if (lane >= off) ve += t;
    }
    if (lane < EBLK) boff_e[lane] = ve - ve0;
    int vn0 = (lane < NBLK) ? totals_n[lane] : 0;
    int vn = vn0;
    #pragma unroll
    for (int off = 1; off < 64; off <<= 1) {
        int t = __shfl_up(vn, off);
        if (lane >= off) vn += t;
    }
    if (lane < NBLK) boff_n[lane] = vn - vn0;
    if (lane == 0) { start_e[0] = 0; start_n[0] = 0; }
}

// ------------- scan phase 3 -------------
__global__ void scan_add(
    int* __restrict__ start_e, const int* __restrict__ boff_e,
    int* __restrict__ start_n, const int* __restrict__ boff_n)
{
    int id = blockIdx.x * 256 + threadIdx.x;
    if (id < M_EDGES) start_e[id + 1] += boff_e[id >> 10];
    else if (id < M_EDGES + N_NODES) {
        int j = id - M_EDGES;
        start_n[j + 1] += boff_n[j >> 10];
    }
}

// ------------- place: CSR lists from precomputed ranks (no atomics) -------------
__global__ void place_kernel(
    const int* __restrict__ node_idx, const int* __restrict__ edge_idx,
    const unsigned* __restrict__ rank_pk,
    const int* __restrict__ start_e, const int* __restrict__ start_n,
    int* __restrict__ list_e, int* __restrict__ list_n)
{
    int e = blockIdx.x * blockDim.x + threadIdx.x;
    if (e >= N_INC) return;
    unsigned pk = rank_pk[e];
    list_e[start_e[edge_idx[e]] + (pk >> 16)] = e;
    list_n[start_n[node_idx[e]] + (pk & 0xFFFFu)] = e;
}

// ------------- rnorm: per-node esum via CSR gather (no atomics) -------------
__global__ void rnorm_kernel(
    const float* __restrict__ ealpha, const int* __restrict__ start_n,
    const int* __restrict__ list_n, float* __restrict__ rnorm)
{
    int n = blockIdx.x * blockDim.x + threadIdx.x;
    if (n >= N_NODES) return;
    int j0 = start_n[n], j1 = start_n[n + 1];
    float s = 0.f;
    for (int j = j0; j < j1; ++j) s += ealpha[list_n[j]];
    rnorm[n] = 1.f / (s + 1e-16f);
}

// ------------- stage 1: gather bf16 xw per hyperedge -> bf16 edge_feat -------------
// weight = ealpha[e] * rnorm[node] computed in metadata phase
__global__ __launch_bounds__(256) void stage1_kernel(
    const ushort* __restrict__ xwb, const int* __restrict__ node_idx,
    const float* __restrict__ ealpha, const float* __restrict__ rnorm,
    const int* __restrict__ start_e, const int* __restrict__ list_e,
    ushort* __restrict__ edge_feat)
{
    int h = blockIdx.x * 4 + (threadIdx.x >> 6);
    if (h >= M_EDGES) return;
    int lane = threadIdx.x & 63;
    int j0 = start_e[h], j1 = start_e[h + 1];
    float4 acc = make_float4(0.f, 0.f, 0.f, 0.f);
    float4 ac2 = make_float4(0.f, 0.f, 0.f, 0.f);
    for (int base = j0; base < j1; base += 64) {
        int cnt = min(64, j1 - base);
        float wv = 0.f; int nv = 0;
        if (lane < cnt) {
            int e = list_e[base + lane];
            int n_ = node_idx[e];
            wv = ealpha[e] * rnorm[n_];
            nv = n_;
        }
        int jj = 0;
        for (; jj + 4 <= cnt; jj += 4) {
            float wg0 = __shfl(wv, jj);     int n0 = __shfl(nv, jj);
            float wg1 = __shfl(wv, jj + 1); int n1 = __shfl(nv, jj + 1);
            float wg2 = __shfl(wv, jj + 2); int n2 = __shfl(nv, jj + 2);
            float wg3 = __shfl(wv, jj + 3); int n3 = __shfl(nv, jj + 3);
            uint2 p0 = *(const uint2*)(xwb + (size_t)n0 * DIM + lane * 4);
            uint2 p1 = *(const uint2*)(xwb + (size_t)n1 * DIM + lane * 4);
            uint2 p2 = *(const uint2*)(xwb + (size_t)n2 * DIM + lane * 4);
            uint2 p3 = *(const uint2*)(xwb + (size_t)n3 * DIM + lane * 4);
            float4 v0 = unp4(p0), v1 = unp4(p1), v2 = unp4(p2), v3 = unp4(p3);
            acc.x += wg0 * v0.x + wg1 * v1.x;  ac2.x += wg2 * v2.x + wg3 * v3.x;
            acc.y += wg0 * v0.y + wg1 * v1.y;  ac2.y += wg2 * v2.y + wg3 * v3.y;
            acc.z += wg0 * v0.z + wg1 * v1.z;  ac2.z += wg2 * v2.z + wg3 * v3.z;
            acc.w += wg0 * v0.w + wg1 * v1.w;  ac2.w += wg2 * v2.w + wg3 * v3.w;
        }
        for (; jj < cnt; ++jj) {
            float wg = __shfl(wv, jj); int n0 = __shfl(nv, jj);
            float4 v = unp4(*(const uint2*)(xwb + (size_t)n0 * DIM + lane * 4));
            acc.x += wg * v.x; acc.y += wg * v.y;
            acc.z += wg * v.z; acc.w += wg * v.w;
        }
    }
    acc.x += ac2.x; acc.y += ac2.y; acc.z += ac2.z; acc.w += ac2.w;
    float binv = (j1 > j0) ? 1.f / (float)(j1 - j0) : 0.f;
    uint2 p;
    p.x = bf16rn(acc.x * binv) | (bf16rn(acc.y * binv) << 16);
    p.y = bf16rn(acc.z * binv) | (bf16rn(acc.w * binv) << 16);
    *(uint2*)(edge_feat + (size_t)h * DIM + lane * 4) = p;
}

// ------------- stage 2: gather bf16 edge_feat per node; rnorm factors out -------------
__global__ __launch_bounds__(256) void stage2_kernel(
    const ushort* __restrict__ edge_feat, const int* __restrict__ edge_idx,
    const float* __restrict__ ealpha, const float* __restrict__ rnorm,
    const int* __restrict__ start_n, const int* __restrict__ list_n,
    const float* __restrict__ bias, float* __restrict__ out)
{
    int n = blockIdx.x * 4 + (threadIdx.x >> 6);
    if (n >= N_NODES) return;
    int lane = threadIdx.x & 63;
    int j0 = start_n[n], j1 = start_n[n + 1];
    float4 acc = make_float4(0.f, 0.f, 0.f, 0.f);
    float4 ac2 = make_float4(0.f, 0.f, 0.f, 0.f);
    for (int base = j0; base < j1; base += 64) {
        int cnt = min(64, j1 - base);
        float wv = 0.f; int hv = 0;
        if (lane < cnt) { int e = list_n[base + lane]; wv = ealpha[e]; hv = edge_idx[e]; }
        int jj = 0;
        for (; jj + 4 <= cnt; jj += 4) {
            float wg0 = __shfl(wv, jj);     int h0 = __shfl(hv, jj);
            float wg1 = __shfl(wv, jj + 1); int h1 = __shfl(hv, jj + 1);
            float wg2 = __shfl(wv, jj + 2); int h2 = __shfl(hv, jj + 2);
            float wg3 = __shfl(wv, jj + 3); int h3 = __shfl(hv, jj + 3);
            uint2 p0 = *(const uint2*)(edge_feat + (size_t)h0 * DIM + lane * 4);
            uint2 p1 = *(const uint2*)(edge_feat + (size_t)h1 * DIM + lane * 4);
            uint2 p2 = *(const uint2*)(edge_feat + (size_t)h2 * DIM + lane * 4);
            uint2 p3 = *(const uint2*)(edge_feat + (size_t)h3 * DIM + lane * 4);
            float4 v0 = unp4(p0), v1 = unp4(p1), v2 = unp4(p2), v3 = unp4(p3);
            acc.x += wg0 * v0.x + wg1 * v1.x;  ac2.x += wg2 * v2.x + wg3 * v3.x;
            acc.y += wg0 * v0.y + wg1 * v1.y;  ac2.y += wg2 * v2.y + wg3 * v3.y;
            acc.z += wg0 * v0.z + wg1 * v1.z;  ac2.z += wg2 * v2.z + wg3 * v3.z;
            acc.w += wg0 * v0.w + wg1 * v1.w;  ac2.w += wg2 * v2.w + wg3 * v3.w;
        }
        for (; jj < cnt; ++jj) {
            float wg = __shfl(wv, jj); int h0 = __shfl(hv, jj);
            float4 v = unp4(*(const uint2*)(edge_feat + (size_t)h0 * DIM + lane * 4));
            acc.x += wg * v.x; acc.y += wg * v.y;
            acc.z += wg * v.z; acc.w += wg * v.w;
        }
    }
    acc.x += ac2.x; acc.y += ac2.y; acc.z += ac2.z; acc.w += ac2.w;
    float sc = (j1 > j0) ? rnorm[n] / (float)(j1 - j0) : 0.f;   // dinv * rnorm
    float4 b = *(const float4*)(bias + lane * 4);
    acc.x = fmaf(acc.x, sc, b.x); acc.y = fmaf(acc.y, sc, b.y);
    acc.z = fmaf(acc.z, sc, b.z); acc.w = fmaf(acc.w, sc, b.w);
    *(float4*)(out + (size_t)n * DIM + lane * 4) = acc;
}

// ------------- BN column stats: float4 + LDS cross-wave reduce -------------
__global__ __launch_bounds__(256) void stats_kernel(
    const float* __restrict__ out, float* __restrict__ stats)
{
    __shared__ float lsum[4][256], lsq[4][256];
    int tid = threadIdx.x, lane = tid & 63, w = tid >> 6;
    int c4 = lane * 4;
    int rows_per = (N_NODES + gridDim.x - 1) / gridDim.x;
    int r0 = blockIdx.x * rows_per;
    int r1 = min(r0 + rows_per, N_NODES);
    float4 s = make_float4(0.f, 0.f, 0.f, 0.f);
    float4 q = make_float4(0.f, 0.f, 0.f, 0.f);
    for (int r = r0 + w; r < r1; r += 4) {
        float4 v = *(const float4*)(out + (size_t)r * DIM + c4);
        s.x += v.x; s.y += v.y; s.z += v.z; s.w += v.w;
        q.x += v.x * v.x; q.y += v.y * v.y; q.z += v.z * v.z; q.w += v.w * v.w;
    }
    *(float4*)&lsum[w][c4] = s;
    *(float4*)&lsq[w][c4] = q;
    __syncthreads();
    if (w == 0) {
        #pragma unroll
        for (int i = 1; i < 4; ++i) {
            s.x += lsum[i][c4]; s.y += lsum[i][c4 + 1]; s.z += lsum[i][c4 + 2]; s.w += lsum[i][c4 + 3];
            q.x += lsq[i][c4];  q.y += lsq[i][c4 + 1];  q.z += lsq[i][c4 + 2];  q.w += lsq[i][c4 + 3];
        }
        atomicAdd(stats + c4 + 0, s.x); atomicAdd(stats + c4 + 1, s.y);
        atomicAdd(stats + c4 + 2, s.z); atomicAdd(stats + c4 + 3, s.w);
        atomicAdd(stats + DIM + c4 + 0, q.x); atomicAdd(stats + DIM + c4 + 1, q.y);
        atomicAdd(stats + DIM + c4 + 2, q.z); atomicAdd(stats + DIM + c4 + 3, q.w);
    }
}

// ------------- BN prep: per-column scale/shift -------------
__global__ void bnprep_kernel(
    const float* __restrict__ stats, const float* __restrict__ gamma,
    const float* __restrict__ beta, float* __restrict__ scale, float* __restrict__ shift)
{
    int c = threadIdx.x;
    float mu = stats[c] * (1.f / N_NODES);
    float var = stats[DIM + c] * (1.f / N_NODES) - mu * mu;
    float sc = gamma[c] * rsqrtf(var + BN_EPS);
    scale[c] = sc;
    shift[c] = beta[c] - mu * sc;
}

// ------------- BN apply + ELU, streaming float4 -------------
__global__ __launch_bounds__(256) void bn_kernel(
    float* __restrict__ out, const float* __restrict__ scale, const float* __restrict__ shift)
{
    int idx = blockIdx.x * 256 + threadIdx.x;       // N*DIM/4 threads
    int c4 = (idx & 63) * 4;
    float4 sc = *(const float4*)(scale + c4);
    float4 sh = *(const float4*)(shift + c4);
    float4 v = ((float4*)out)[idx];
    v.x = fmaf(v.x, sc.x, sh.x); v.y = fmaf(v.y, sc.y, sh.y);
    v.z = fmaf(v.z, sc.z, sh.z); v.w = fmaf(v.w, sc.w, sh.w);
    v.x = v.x > 0.f ? v.x : __expf(v.x) - 1.f;
    v.y = v.y > 0.f ? v.y : __expf(v.y) - 1.f;
    v.z = v.z > 0.f ? v.z : __expf(v.z) - 1.f;
    v.w = v.w > 0.f ? v.w : __expf(v.w) - 1.f;
    ((float4*)out)[idx] = v;
}

extern "C" void kernel_launch(void* const* d_in, const int* in_sizes, int n_in,
                              void* d_out, int out_size, void* d_ws, size_t ws_size,
                              hipStream_t stream)
{
    const float* x        = (const float*)d_in[0];
    const int*   node_idx = (const int*)d_in[1];
    const int*   edge_idx = (const int*)d_in[2];
    const float* W        = (const float*)d_in[4];
    const float* att      = (const float*)d_in[5];
    const float* bias     = (const float*)d_in[6];
    const float* gamma    = (const float*)d_in[7];
    const float* beta     = (const float*)d_in[8];
    float* out = (float*)d_out;
    ushort* xwb = (ushort*)d_out;     // bf16 xw in first 25.6 MB of d_out; overwritten by stage2

    ushort* edge_feat = (ushort*)d_ws;                          // M*DIM bf16
    // ---- zeroed block (contiguous) ----
    int*   cnt_e   = (int*)(edge_feat + (size_t)M_EDGES * DIM); // M
    int*   cnt_n   = cnt_e + M_EDGES;                           // N
    float* stats   = (float*)(cnt_n + N_NODES);                 // 2*DIM
    // ---- not zeroed ----
    float* s1      = stats + 2 * DIM;                           // N
    float* s2      = s1 + N_NODES;                              // N
    float* ealpha  = s2 + N_NODES;                              // E
    unsigned* rank_pk = (unsigned*)(ealpha + N_INC);            // E
    float* rnorm   = (float*)(rank_pk + N_INC);                 // N
    int*   start_e = (int*)(rnorm + N_NODES);                   // M+1
    int*   start_n = start_e + M_EDGES + 1;                     // N+1
    int*   list_e  = start_n + N_NODES + 1;                     // E
    int*   list_n  = list_e + N_INC;                            // E
    ushort* WT     = (ushort*)(list_n + N_INC);                 // 256*256 bf16
    int*   totals_e = (int*)(WT + 256 * 256);                   // EBLK
    int*   boff_e   = totals_e + EBLK;                          // EBLK
    int*   totals_n = boff_e + EBLK;                            // NBLK
    int*   boff_n   = totals_n + NBLK;                          // NBLK
    float* scale    = (float*)(boff_n + NBLK);                  // DIM
    float* shift    = scale + DIM;                              // DIM

    hipMemsetAsync(cnt_e, 0, (size_t)(M_EDGES + N_NODES + 2 * DIM) * 4, stream);

    wt_kernel<<<256, 256, 0, stream>>>(W, WT);
    gemm_persist<<<(N_NODES + GBM - 1) / GBM, 512, 0, stream>>>(x, WT, att, xwb, s1, s2);
    rank_kernel<<<(N_INC + 255) / 256, 256, 0, stream>>>(node_idx, edge_idx, s1, s2, ealpha, rank_pk, cnt_n, cnt_e);
    scan_partial<<<EBLK + NBLK, 1024, 0, stream>>>(cnt_e, start_e, totals_e, cnt_n, start_n, totals_n);
    scan_totals<<<1, 64, 0, stream>>>(totals_e, boff_e, totals_n, boff_n, start_e, start_n);
    scan_add<<<(M_EDGES + N_NODES + 255) / 256, 256, 0, stream>>>(start_e, boff_e, start_n, boff_n);
    place_kernel<<<(N_INC + 255) / 256, 256, 0, stream>>>(node_idx, edge_idx, rank_pk, start_e, start_n, list_e, list_n);
    rnorm_kernel<<<(N_NODES + 255) / 256, 256, 0, stream>>>(ealpha, start_n, list_n, rnorm);
    stage1_kernel<<<(M_EDGES + 3) / 4, 256, 0, stream>>>(xwb, node_idx, ealpha, rnorm, start_e, list_e, edge_feat);
    stage2_kernel<<<(N_NODES + 3) / 4, 256, 0, stream>>>(edge_feat, edge_idx, ealpha, rnorm, start_n, list_n, bias, out);
    stats_kernel<<<128, 256, 0, stream>>>(out, stats);
    bnprep_kernel<<<1, 256, 0, stream>>>(stats, gamma, beta, scale, shift);
    bn_kernel<<<N_NODES * DIM / 4 / 256, 256, 0, stream>>>(out, scale, shift);
}

// Round 11
// 207.367 us; speedup vs baseline: 1.3289x; 1.0001x over previous
//
#include <hip/hip_runtime.h>

#define N_NODES 50000
#define N_INC   300000
#define RHALF   150000
#define DIM     256
#define M_EDGES 20000
#define NEG_SLOPE 0.2f
#define BN_EPS  1e-5f
#define EBLK 20
#define NBLK 49

typedef __attribute__((ext_vector_type(8))) short short8;
typedef __attribute__((ext_vector_type(4))) float f32x4;

__device__ __forceinline__ unsigned bf16rn(float f) {
    unsigned u = __float_as_uint(f);
    return (u + 0x7FFFu + ((u >> 16) & 1u)) >> 16;   // round-to-nearest-even
}
__device__ __forceinline__ float4 unp4(uint2 p) {
    return make_float4(__uint_as_float(p.x << 16),
                       __uint_as_float(p.x & 0xFFFF0000u),
                       __uint_as_float(p.y << 16),
                       __uint_as_float(p.y & 0xFFFF0000u));
}

// ------------- W[k][n] f32 -> WT[n][k] bf16 -------------
__global__ void wt_kernel(const float* __restrict__ W, ushort* __restrict__ WT)
{
    int i = blockIdx.x * 256 + threadIdx.x;          // 65536
    int k = i >> 8, n = i & 255;
    WT[n * 256 + k] = (ushort)bf16rn(W[i]);
}

// ---------------- persistent-W MFMA GEMM: whole WT (128 KB) in LDS ----------------
// LDS-staged epilogue: coalesced uint4 stores of bf16 xw.
#define GBM 256   // rows per block (8 waves x 32)
__global__ __launch_bounds__(512, 2) void gemm_persist(
    const float* __restrict__ A, const ushort* __restrict__ WT,
    const float* __restrict__ att,
    ushort* __restrict__ xwb, float* __restrict__ s1, float* __restrict__ s2)
{
    __shared__ __align__(16) char Bs[131072];   // [256 cols][256 k] bf16, XOR-swizzled
    int tid = threadIdx.x;
    int lane = tid & 63, w = tid >> 6;

    #pragma unroll
    for (int i = 0; i < 16; ++i) {
        int flat = tid + 512 * i;
        int n = flat >> 5, kc = flat & 31;
        uint4 v = *(const uint4*)(WT + n * 256 + kc * 8);
        int off = n * 512 + ((kc * 16) ^ ((n & 7) << 4));
        *(uint4*)(Bs + off) = v;
    }
    __syncthreads();

    int row0 = blockIdx.x * GBM + w * 32;

    // A fragments: 2 strips x 8 k-chunks, direct global->reg->bf16
    short8 afrag[2][8];
    #pragma unroll
    for (int j = 0; j < 8; ++j) {
        #pragma unroll
        for (int s = 0; s < 2; ++s) {
            int row = row0 + s * 16 + (lane & 15);
            float4 u0 = make_float4(0.f, 0.f, 0.f, 0.f), u1 = u0;
            if (row < N_NODES) {
                const float* p = A + (size_t)row * DIM + j * 32 + (lane >> 4) * 8;
                u0 = *(const float4*)p;
                u1 = *(const float4*)(p + 4);
            }
            uint4 q;
            q.x = bf16rn(u0.x) | (bf16rn(u0.y) << 16);
            q.y = bf16rn(u0.z) | (bf16rn(u0.w) << 16);
            q.z = bf16rn(u1.x) | (bf16rn(u1.y) << 16);
            q.w = bf16rn(u1.z) | (bf16rn(u1.w) << 16);
            afrag[s][j] = *(short8*)&q;
        }
    }

    f32x4 acc[2][16] = {};
    #pragma unroll
    for (int j = 0; j < 8; ++j) {
        int kb = j * 64 + (lane >> 4) * 16;
        #pragma unroll
        for (int c = 0; c < 16; ++c) {
            int col = c * 16 + (lane & 15);
            short8 b = *(const short8*)(Bs + col * 512 + (kb ^ ((col & 7) << 4)));
            acc[0][c] = __builtin_amdgcn_mfma_f32_16x16x32_bf16(afrag[0][j], b, acc[0][c], 0, 0, 0);
            acc[1][c] = __builtin_amdgcn_mfma_f32_16x16x32_bf16(afrag[1][j], b, acc[1][c], 0, 0, 0);
        }
    }

    // fused attention dots from f32 acc (in-wave 16-lane reduce, plain stores)
    float p1a[2][4] = {}, p2a[2][4] = {};
    #pragma unroll
    for (int c = 0; c < 16; ++c) {
        int col = c * 16 + (lane & 15);
        float a1 = att[col], a2 = att[DIM + col];
        #pragma unroll
        for (int s = 0; s < 2; ++s)
            #pragma unroll
            for (int r = 0; r < 4; ++r) {
                p1a[s][r] += acc[s][c][r] * a1;
                p2a[s][r] += acc[s][c][r] * a2;
            }
    }
    #pragma unroll
    for (int s = 0; s < 2; ++s)
        #pragma unroll
        for (int r = 0; r < 4; ++r) {
            float p1 = p1a[s][r], p2 = p2a[s][r];
            #pragma unroll
            for (int msk = 1; msk < 16; msk <<= 1) {
                p1 += __shfl_xor(p1, msk);
                p2 += __shfl_xor(p2, msk);
            }
            int row = row0 + s * 16 + (lane >> 4) * 4 + r;
            if ((lane & 15) == 0 && row < N_NODES) {
                s1[row] = p1;
                s2[row] = p2;
            }
        }

    // LDS-staged epilogue: wave-private [32][256] ushort slice of Bs
    __syncthreads();                       // all waves done reading Bs
    char* slice = Bs + w * 16384;
    #pragma unroll
    for (int c = 0; c < 16; ++c) {
        #pragma unroll
        for (int s = 0; s < 2; ++s)
            #pragma unroll
            for (int r = 0; r < 4; ++r) {
                int lrow = s * 16 + (lane >> 4) * 4 + r;
                int col = c * 16 + (lane & 15);
                *(ushort*)(slice + lrow * 512 + col * 2) = (ushort)bf16rn(acc[s][c][r]);
            }
    }
    __syncthreads();
    #pragma unroll
    for (int i = 0; i < 16; ++i) {
        int flat = lane + 64 * i;
        int lrow = flat >> 5, c16 = flat & 31;
        int row = row0 + lrow;
        if (row < N_NODES) {
            uint4 v = *(const uint4*)(slice + lrow * 512 + c16 * 16);
            *(uint4*)(xwb + (size_t)row * DIM + c16 * 8) = v;
        }
    }
}

// ------------- rank: ealpha + histogram-with-rank, 2 incidences/thread -------------
__global__ void rank_kernel(
    const int* __restrict__ node_idx, const int* __restrict__ edge_idx,
    const float* __restrict__ s1, const float* __restrict__ s2,
    float* __restrict__ ealpha, unsigned* __restrict__ rank_pk,
    int* __restrict__ cnt_n, int* __restrict__ cnt_e)
{
    int e = blockIdx.x * blockDim.x + threadIdx.x;
    if (e >= RHALF) return;
    int e2 = e + RHALF;
    int n0 = node_idx[e],  h0 = edge_idx[e];
    int n1 = node_idx[e2], h1 = edge_idx[e2];
    float a0 = s1[n0] + s2[h0];
    float a1 = s1[n1] + s2[h1];
    a0 = a0 > 0.f ? a0 : NEG_SLOPE * a0;
    a1 = a1 > 0.f ? a1 : NEG_SLOPE * a1;
    ealpha[e]  = __expf(a0);              // no max-subtraction: |a| small, safe in f32
    ealpha[e2] = __expf(a1);
    unsigned rn0 = (unsigned)atomicAdd(cnt_n + n0, 1);
    unsigned re0 = (unsigned)atomicAdd(cnt_e + h0, 1);
    unsigned rn1 = (unsigned)atomicAdd(cnt_n + n1, 1);
    unsigned re1 = (unsigned)atomicAdd(cnt_e + h1, 1);
    rank_pk[e]  = (re0 << 16) | rn0;
    rank_pk[e2] = (re1 << 16) | rn1;
}

// ------------- scan phase 1 -------------
__global__ __launch_bounds__(1024) void scan_partial(
    const int* __restrict__ cnt_e, int* __restrict__ start_e, int* __restrict__ totals_e,
    const int* __restrict__ cnt_n, int* __restrict__ start_n, int* __restrict__ totals_n)
{
    int b = blockIdx.x;
    const int* cnt; int* start; int* totals; int n; int cb;
    if (b < EBLK) { cnt = cnt_e; start = start_e; totals = totals_e; n = M_EDGES; cb = b; }
    else          { cnt = cnt_n; start = start_n; totals = totals_n; n = N_NODES; cb = b - EBLK; }
    int tid = threadIdx.x, lane = tid & 63, wid = tid >> 6;
    int i = cb * 1024 + tid;
    int v = (i < n) ? cnt[i] : 0;
    #pragma unroll
    for (int off = 1; off < 64; off <<= 1) {
        int t = __shfl_up(v, off);
        if (lane >= off) v += t;
    }
    __shared__ int wsum[16];
    if (lane == 63) wsum[wid] = v;
    __syncthreads();
    if (wid == 0 && lane < 16) {
        int s = wsum[lane];
        #pragma unroll
        for (int off = 1; off < 16; off <<= 1) {
            int t = __shfl_up(s, off);
            if (lane >= off) s += t;
        }
        wsum[lane] = s;
    }
    __syncthreads();
    if (wid > 0) v += wsum[wid - 1];
    if (i < n) start[i + 1] = v;
    if (tid == 1023) totals[cb] = v;
}

// ------------- scan phase 2+3 fused: local totals-prefix + offset add -------------
__global__ __launch_bounds__(256) void scan_add(
    int* __restrict__ start_e, const int* __restrict__ totals_e,
    int* __restrict__ start_n, const int* __restrict__ totals_n)
{
    __shared__ int lboff_e[EBLK], lboff_n[NBLK];
    int tid = threadIdx.x;
    if (tid < 64) {
        int lane = tid;
        int ve0 = (lane < EBLK) ? totals_e[lane] : 0;
        int ve = ve0;
        #pragma unroll
        for (int off = 1; off < 64; off <<= 1) {
            int t = __shfl_up(ve, off);
            if (lane >= off) ve += t;
        }
        if (lane < EBLK) lboff_e[lane] = ve - ve0;
        int vn0 = (lane < NBLK) ? totals_n[lane] : 0;
        int vn = vn0;
        #pragma unroll
        for (int off = 1; off < 64; off <<= 1) {
            int t = __shfl_up(vn, off);
            if (lane >= off) vn += t;
        }
        if (lane < NBLK) lboff_n[lane] = vn - vn0;
    }
    __syncthreads();
    int id = blockIdx.x * 256 + tid;
    if (id == 0) start_e[0] = 0;
    if (id < M_EDGES) start_e[id + 1] += lboff_e[id >> 10];
    else if (id < M_EDGES + N_NODES) {
        int j = id - M_EDGES;
        if (j == 0) start_n[0] = 0;
        start_n[j + 1] += lboff_n[j >> 10];
    }
}

// ------------- place: CSR lists from precomputed ranks (no atomics) -------------
__global__ void place_kernel(
    const int* __restrict__ node_idx, const int* __restrict__ edge_idx,
    const unsigned* __restrict__ rank_pk,
    const int* __restrict__ start_e, const int* __restrict__ start_n,
    int* __restrict__ list_e, int* __restrict__ list_n)
{
    int e = blockIdx.x * blockDim.x + threadIdx.x;
    if (e >= N_INC) return;
    unsigned pk = rank_pk[e];
    list_e[start_e[edge_idx[e]] + (pk >> 16)] = e;
    list_n[start_n[node_idx[e]] + (pk & 0xFFFFu)] = e;
}

// ------------- rnorm: per-node esum via CSR gather (no atomics) -------------
__global__ void rnorm_kernel(
    const float* __restrict__ ealpha, const int* __restrict__ start_n,
    const int* __restrict__ list_n, float* __restrict__ rnorm)
{
    int n = blockIdx.x * blockDim.x + threadIdx.x;
    if (n >= N_NODES) return;
    int j0 = start_n[n], j1 = start_n[n + 1];
    float s = 0.f;
    for (int j = j0; j < j1; ++j) s += ealpha[list_n[j]];
    rnorm[n] = 1.f / (s + 1e-16f);
}

// ------------- stage 1: gather bf16 xw per hyperedge -> bf16 edge_feat -------------
__global__ __launch_bounds__(256) void stage1_kernel(
    const ushort* __restrict__ xwb, const int* __restrict__ node_idx,
    const float* __restrict__ ealpha, const float* __restrict__ rnorm,
    const int* __restrict__ start_e, const int* __restrict__ list_e,
    ushort* __restrict__ edge_feat)
{
    int h = blockIdx.x * 4 + (threadIdx.x >> 6);
    if (h >= M_EDGES) return;
    int lane = threadIdx.x & 63;
    int j0 = start_e[h], j1 = start_e[h + 1];
    float4 acc = make_float4(0.f, 0.f, 0.f, 0.f);
    float4 ac2 = make_float4(0.f, 0.f, 0.f, 0.f);
    for (int base = j0; base < j1; base += 64) {
        int cnt = min(64, j1 - base);
        float wv = 0.f; int nv = 0;
        if (lane < cnt) {
            int e = list_e[base + lane];
            int n_ = node_idx[e];
            wv = ealpha[e] * rnorm[n_];
            nv = n_;
        }
        int jj = 0;
        for (; jj + 4 <= cnt; jj += 4) {
            float wg0 = __shfl(wv, jj);     int n0 = __shfl(nv, jj);
            float wg1 = __shfl(wv, jj + 1); int n1 = __shfl(nv, jj + 1);
            float wg2 = __shfl(wv, jj + 2); int n2 = __shfl(nv, jj + 2);
            float wg3 = __shfl(wv, jj + 3); int n3 = __shfl(nv, jj + 3);
            uint2 p0 = *(const uint2*)(xwb + (size_t)n0 * DIM + lane * 4);
            uint2 p1 = *(const uint2*)(xwb + (size_t)n1 * DIM + lane * 4);
            uint2 p2 = *(const uint2*)(xwb + (size_t)n2 * DIM + lane * 4);
            uint2 p3 = *(const uint2*)(xwb + (size_t)n3 * DIM + lane * 4);
            float4 v0 = unp4(p0), v1 = unp4(p1), v2 = unp4(p2), v3 = unp4(p3);
            acc.x += wg0 * v0.x + wg1 * v1.x;  ac2.x += wg2 * v2.x + wg3 * v3.x;
            acc.y += wg0 * v0.y + wg1 * v1.y;  ac2.y += wg2 * v2.y + wg3 * v3.y;
            acc.z += wg0 * v0.z + wg1 * v1.z;  ac2.z += wg2 * v2.z + wg3 * v3.z;
            acc.w += wg0 * v0.w + wg1 * v1.w;  ac2.w += wg2 * v2.w + wg3 * v3.w;
        }
        for (; jj < cnt; ++jj) {
            float wg = __shfl(wv, jj); int n0 = __shfl(nv, jj);
            float4 v = unp4(*(const uint2*)(xwb + (size_t)n0 * DIM + lane * 4));
            acc.x += wg * v.x; acc.y += wg * v.y;
            acc.z += wg * v.z; acc.w += wg * v.w;
        }
    }
    acc.x += ac2.x; acc.y += ac2.y; acc.z += ac2.z; acc.w += ac2.w;
    float binv = (j1 > j0) ? 1.f / (float)(j1 - j0) : 0.f;
    uint2 p;
    p.x = bf16rn(acc.x * binv) | (bf16rn(acc.y * binv) << 16);
    p.y = bf16rn(acc.z * binv) | (bf16rn(acc.w * binv) << 16);
    *(uint2*)(edge_feat + (size_t)h * DIM + lane * 4) = p;
}

// ------------- stage 2: gather bf16 edge_feat per node; rnorm factors out -------------
__global__ __launch_bounds__(256) void stage2_kernel(
    const ushort* __restrict__ edge_feat, const int* __restrict__ edge_idx,
    const float* __restrict__ ealpha, const float* __restrict__ rnorm,
    const int* __restrict__ start_n, const int* __restrict__ list_n,
    const float* __restrict__ bias, float* __restrict__ out)
{
    int n = blockIdx.x * 4 + (threadIdx.x >> 6);
    if (n >= N_NODES) return;
    int lane = threadIdx.x & 63;
    int j0 = start_n[n], j1 = start_n[n + 1];
    float4 acc = make_float4(0.f, 0.f, 0.f, 0.f);
    float4 ac2 = make_float4(0.f, 0.f, 0.f, 0.f);
    for (int base = j0; base < j1; base += 64) {
        int cnt = min(64, j1 - base);
        float wv = 0.f; int hv = 0;
        if (lane < cnt) { int e = list_n[base + lane]; wv = ealpha[e]; hv = edge_idx[e]; }
        int jj = 0;
        for (; jj + 4 <= cnt; jj += 4) {
            float wg0 = __shfl(wv, jj);     int h0 = __shfl(hv, jj);
            float wg1 = __shfl(wv, jj + 1); int h1 = __shfl(hv, jj + 1);
            float wg2 = __shfl(wv, jj + 2); int h2 = __shfl(hv, jj + 2);
            float wg3 = __shfl(wv, jj + 3); int h3 = __shfl(hv, jj + 3);
            uint2 p0 = *(const uint2*)(edge_feat + (size_t)h0 * DIM + lane * 4);
            uint2 p1 = *(const uint2*)(edge_feat + (size_t)h1 * DIM + lane * 4);
            uint2 p2 = *(const uint2*)(edge_feat + (size_t)h2 * DIM + lane * 4);
            uint2 p3 = *(const uint2*)(edge_feat + (size_t)h3 * DIM + lane * 4);
            float4 v0 = unp4(p0), v1 = unp4(p1), v2 = unp4(p2), v3 = unp4(p3);
            acc.x += wg0 * v0.x + wg1 * v1.x;  ac2.x += wg2 * v2.x + wg3 * v3.x;
            acc.y += wg0 * v0.y + wg1 * v1.y;  ac2.y += wg2 * v2.y + wg3 * v3.y;
            acc.z += wg0 * v0.z + wg1 * v1.z;  ac2.z += wg2 * v2.z + wg3 * v3.z;
            acc.w += wg0 * v0.w + wg1 * v1.w;  ac2.w += wg2 * v2.w + wg3 * v3.w;
        }
        for (; jj < cnt; ++jj) {
            float wg = __shfl(wv, jj); int h0 = __shfl(hv, jj);
            float4 v = unp4(*(const uint2*)(edge_feat + (size_t)h0 * DIM + lane * 4));
            acc.x += wg * v.x; acc.y += wg * v.y;
            acc.z += wg * v.z; acc.w += wg * v.w;
        }
    }
    acc.x += ac2.x; acc.y += ac2.y; acc.z += ac2.z; acc.w += ac2.w;
    float sc = (j1 > j0) ? rnorm[n] / (float)(j1 - j0) : 0.f;   // dinv * rnorm
    float4 b = *(const float4*)(bias + lane * 4);
    acc.x = fmaf(acc.x, sc, b.x); acc.y = fmaf(acc.y, sc, b.y);
    acc.z = fmaf(acc.z, sc, b.z); acc.w = fmaf(acc.w, sc, b.w);
    *(float4*)(out + (size_t)n * DIM + lane * 4) = acc;
}

// ------------- BN column stats: float4 + LDS cross-wave reduce -------------
__global__ __launch_bounds__(256) void stats_kernel(
    const float* __restrict__ out, float* __restrict__ stats)
{
    __shared__ float lsum[4][256], lsq[4][256];
    int tid = threadIdx.x, lane = tid & 63, w = tid >> 6;
    int c4 = lane * 4;
    int rows_per = (N_NODES + gridDim.x - 1) / gridDim.x;
    int r0 = blockIdx.x * rows_per;
    int r1 = min(r0 + rows_per, N_NODES);
    float4 s = make_float4(0.f, 0.f, 0.f, 0.f);
    float4 q = make_float4(0.f, 0.f, 0.f, 0.f);
    for (int r = r0 + w; r < r1; r += 4) {
        float4 v = *(const float4*)(out + (size_t)r * DIM + c4);
        s.x += v.x; s.y += v.y; s.z += v.z; s.w += v.w;
        q.x += v.x * v.x; q.y += v.y * v.y; q.z += v.z * v.z; q.w += v.w * v.w;
    }
    *(float4*)&lsum[w][c4] = s;
    *(float4*)&lsq[w][c4] = q;
    __syncthreads();
    if (w == 0) {
        #pragma unroll
        for (int i = 1; i < 4; ++i) {
            s.x += lsum[i][c4]; s.y += lsum[i][c4 + 1]; s.z += lsum[i][c4 + 2]; s.w += lsum[i][c4 + 3];
            q.x += lsq[i][c4];  q.y += lsq[i][c4 + 1];  q.z += lsq[i][c4 + 2];  q.w += lsq[i][c4 + 3];
        }
        atomicAdd(stats + c4 + 0, s.x); atomicAdd(stats + c4 + 1, s.y);
        atomicAdd(stats + c4 + 2, s.z); atomicAdd(stats + c4 + 3, s.w);
        atomicAdd(stats + DIM + c4 + 0, q.x); atomicAdd(stats + DIM + c4 + 1, q.y);
        atomicAdd(stats + DIM + c4 + 2, q.z); atomicAdd(stats + DIM + c4 + 3, q.w);
    }
}

// ------------- BN prep: per-column scale/shift -------------
__global__ void bnprep_kernel(
    const float* __restrict__ stats, const float* __restrict__ gamma,
    const float* __restrict__ beta, float* __restrict__ scale, float* __restrict__ shift)
{
    int c = threadIdx.x;
    float mu = stats[c] * (1.f / N_NODES);
    float var = stats[DIM + c] * (1.f / N_NODES) - mu * mu;
    float sc = gamma[c] * rsqrtf(var + BN_EPS);
    scale[c] = sc;
    shift[c] = beta[c] - mu * sc;
}

// ------------- BN apply + ELU, streaming float4 -------------
__global__ __launch_bounds__(256) void bn_kernel(
    float* __restrict__ out, const float* __restrict__ scale, const float* __restrict__ shift)
{
    int idx = blockIdx.x * 256 + threadIdx.x;       // N*DIM/4 threads
    int c4 = (idx & 63) * 4;
    float4 sc = *(const float4*)(scale + c4);
    float4 sh = *(const float4*)(shift + c4);
    float4 v = ((float4*)out)[idx];
    v.x = fmaf(v.x, sc.x, sh.x); v.y = fmaf(v.y, sc.y, sh.y);
    v.z = fmaf(v.z, sc.z, sh.z); v.w = fmaf(v.w, sc.w, sh.w);
    v.x = v.x > 0.f ? v.x : __expf(v.x) - 1.f;
    v.y = v.y > 0.f ? v.y : __expf(v.y) - 1.f;
    v.z = v.z > 0.f ? v.z : __expf(v.z) - 1.f;
    v.w = v.w > 0.f ? v.w : __expf(v.w) - 1.f;
    ((float4*)out)[idx] = v;
}

extern "C" void kernel_launch(void* const* d_in, const int* in_sizes, int n_in,
                              void* d_out, int out_size, void* d_ws, size_t ws_size,
                              hipStream_t stream)
{
    const float* x        = (const float*)d_in[0];
    const int*   node_idx = (const int*)d_in[1];
    const int*   edge_idx = (const int*)d_in[2];
    const float* W        = (const float*)d_in[4];
    const float* att      = (const float*)d_in[5];
    const float* bias     = (const float*)d_in[6];
    const float* gamma    = (const float*)d_in[7];
    const float* beta     = (const float*)d_in[8];
    float* out = (float*)d_out;
    ushort* xwb = (ushort*)d_out;     // bf16 xw in first 25.6 MB of d_out; overwritten by stage2

    ushort* edge_feat = (ushort*)d_ws;                          // M*DIM bf16
    // ---- zeroed block (contiguous) ----
    int*   cnt_e   = (int*)(edge_feat + (size_t)M_EDGES * DIM); // M
    int*   cnt_n   = cnt_e + M_EDGES;                           // N
    float* stats   = (float*)(cnt_n + N_NODES);                 // 2*DIM
    // ---- not zeroed ----
    float* s1      = stats + 2 * DIM;                           // N
    float* s2      = s1 + N_NODES;                              // N
    float* ealpha  = s2 + N_NODES;                              // E
    unsigned* rank_pk = (unsigned*)(ealpha + N_INC);            // E
    float* rnorm   = (float*)(rank_pk + N_INC);                 // N
    int*   start_e = (int*)(rnorm + N_NODES);                   // M+1
    int*   start_n = start_e + M_EDGES + 1;                     // N+1
    int*   list_e  = start_n + N_NODES + 1;                     // E
    int*   list_n  = list_e + N_INC;                            // E
    ushort* WT     = (ushort*)(list_n + N_INC);                 // 256*256 bf16
    int*   totals_e = (int*)(WT + 256 * 256);                   // EBLK
    int*   totals_n = totals_e + EBLK;                          // NBLK
    float* scale    = (float*)(totals_n + NBLK);                // DIM
    float* shift    = scale + DIM;                              // DIM

    hipMemsetAsync(cnt_e, 0, (size_t)(M_EDGES + N_NODES + 2 * DIM) * 4, stream);

    wt_kernel<<<256, 256, 0, stream>>>(W, WT);
    gemm_persist<<<(N_NODES + GBM - 1) / GBM, 512, 0, stream>>>(x, WT, att, xwb, s1, s2);
    rank_kernel<<<(RHALF + 255) / 256, 256, 0, stream>>>(node_idx, edge_idx, s1, s2, ealpha, rank_pk, cnt_n, cnt_e);
    scan_partial<<<EBLK + NBLK, 1024, 0, stream>>>(cnt_e, start_e, totals_e, cnt_n, start_n, totals_n);
    scan_add<<<(M_EDGES + N_NODES + 255) / 256, 256, 0, stream>>>(start_e, totals_e, start_n, totals_n);
    place_kernel<<<(N_INC + 255) / 256, 256, 0, stream>>>(node_idx, edge_idx, rank_pk, start_e, start_n, list_e, list_n);
    rnorm_kernel<<<(N_NODES + 255) / 256, 256, 0, stream>>>(ealpha, start_n, list_n, rnorm);
    stage1_kernel<<<(M_EDGES + 3) / 4, 256, 0, stream>>>(xwb, node_idx, ealpha, rnorm, start_e, list_e, edge_feat);
    stage2_kernel<<<(N_NODES + 3) / 4, 256, 0, stream>>>(edge_feat, edge_idx, ealpha, rnorm, start_n, list_n, bias, out);
    stats_kernel<<<200, 256, 0, stream>>>(out, stats);
    bnprep_kernel<<<1, 256, 0, stream>>>(stats, gamma, beta, scale, shift);
    bn_kernel<<<N_NODES * DIM / 4 / 256, 256, 0, stream>>>(out, scale, shift);
}

// Round 12
// 199.717 us; speedup vs baseline: 1.3798x; 1.0383x over previous
//
#include <hip/hip_runtime.h>

#define N_NODES 50000
#define N_INC   300000
#define RHALF   150000
#define DIM     256
#define M_EDGES 20000
#define NEG_SLOPE 0.2f
#define BN_EPS  1e-5f
#define EBLK 20
#define NBLK 49
#define ZERO_INTS (M_EDGES + N_NODES + 2 * DIM)

typedef __attribute__((ext_vector_type(8))) short short8;
typedef __attribute__((ext_vector_type(4))) float f32x4;

__device__ __forceinline__ unsigned bf16rn(float f) {
    unsigned u = __float_as_uint(f);
    return (u + 0x7FFFu + ((u >> 16) & 1u)) >> 16;   // round-to-nearest-even
}
__device__ __forceinline__ float4 unp4(uint2 p) {
    return make_float4(__uint_as_float(p.x << 16),
                       __uint_as_float(p.x & 0xFFFF0000u),
                       __uint_as_float(p.y << 16),
                       __uint_as_float(p.y & 0xFFFF0000u));
}

// ------------- W[k][n] f32 -> WT[n][k] bf16, fused counter zeroing -------------
__global__ void wt_kernel(const float* __restrict__ W, ushort* __restrict__ WT,
                          int* __restrict__ zero_base)
{
    int i = blockIdx.x * 256 + threadIdx.x;          // grid 280 -> 71680 threads
    if (i < 65536) {
        int k = i >> 8, n = i & 255;
        WT[n * 256 + k] = (ushort)bf16rn(W[i]);
    }
    if (i < ZERO_INTS) zero_base[i] = 0;
}

// ---------------- persistent-W MFMA GEMM: whole WT (128 KB) in LDS ----------------
#define GBM 256   // rows per block (8 waves x 32)
__global__ __launch_bounds__(512, 2) void gemm_persist(
    const float* __restrict__ A, const ushort* __restrict__ WT,
    const float* __restrict__ att,
    ushort* __restrict__ xwb, float* __restrict__ s1, float* __restrict__ s2)
{
    __shared__ __align__(16) char Bs[131072];   // [256 cols][256 k] bf16, XOR-swizzled
    int tid = threadIdx.x;
    int lane = tid & 63, w = tid >> 6;
    int row0 = blockIdx.x * GBM + w * 32;

    // strip-0 raw A loads issued BEFORE staging (HBM latency hides under staging)
    int r0c = min(row0 + (lane & 15), N_NODES - 1);
    const float* ap0 = A + (size_t)r0c * DIM + (lane >> 4) * 8;
    float4 araw[16];
    #pragma unroll
    for (int j = 0; j < 8; ++j) {
        araw[2 * j]     = *(const float4*)(ap0 + j * 32);
        araw[2 * j + 1] = *(const float4*)(ap0 + j * 32 + 4);
    }

    // stage whole WT
    #pragma unroll
    for (int i = 0; i < 16; ++i) {
        int flat = tid + 512 * i;
        int n = flat >> 5, kc = flat & 31;
        uint4 v = *(const uint4*)(WT + n * 256 + kc * 8);
        int off = n * 512 + ((kc * 16) ^ ((n & 7) << 4));
        *(uint4*)(Bs + off) = v;
    }
    __syncthreads();

    // convert strip 0; load+convert strip 1
    short8 afrag[2][8];
    #pragma unroll
    for (int j = 0; j < 8; ++j) {
        uint4 q;
        q.x = bf16rn(araw[2 * j].x)     | (bf16rn(araw[2 * j].y) << 16);
        q.y = bf16rn(araw[2 * j].z)     | (bf16rn(araw[2 * j].w) << 16);
        q.z = bf16rn(araw[2 * j + 1].x) | (bf16rn(araw[2 * j + 1].y) << 16);
        q.w = bf16rn(araw[2 * j + 1].z) | (bf16rn(araw[2 * j + 1].w) << 16);
        afrag[0][j] = *(short8*)&q;
    }
    int r1c = min(row0 + 16 + (lane & 15), N_NODES - 1);
    const float* ap1 = A + (size_t)r1c * DIM + (lane >> 4) * 8;
    #pragma unroll
    for (int j = 0; j < 8; ++j) {
        float4 u0 = *(const float4*)(ap1 + j * 32);
        float4 u1 = *(const float4*)(ap1 + j * 32 + 4);
        uint4 q;
        q.x = bf16rn(u0.x) | (bf16rn(u0.y) << 16);
        q.y = bf16rn(u0.z) | (bf16rn(u0.w) << 16);
        q.z = bf16rn(u1.x) | (bf16rn(u1.y) << 16);
        q.w = bf16rn(u1.z) | (bf16rn(u1.w) << 16);
        afrag[1][j] = *(short8*)&q;
    }

    f32x4 acc[2][16] = {};
    #pragma unroll
    for (int j = 0; j < 8; ++j) {
        int kb = j * 64 + (lane >> 4) * 16;
        #pragma unroll
        for (int c = 0; c < 16; ++c) {
            int col = c * 16 + (lane & 15);
            short8 b = *(const short8*)(Bs + col * 512 + (kb ^ ((col & 7) << 4)));
            acc[0][c] = __builtin_amdgcn_mfma_f32_16x16x32_bf16(afrag[0][j], b, acc[0][c], 0, 0, 0);
            acc[1][c] = __builtin_amdgcn_mfma_f32_16x16x32_bf16(afrag[1][j], b, acc[1][c], 0, 0, 0);
        }
    }

    // fused attention dots (in-wave 16-lane reduce, plain stores)
    float p1a[2][4] = {}, p2a[2][4] = {};
    #pragma unroll
    for (int c = 0; c < 16; ++c) {
        int col = c * 16 + (lane & 15);
        float a1 = att[col], a2 = att[DIM + col];
        #pragma unroll
        for (int s = 0; s < 2; ++s)
            #pragma unroll
            for (int r = 0; r < 4; ++r) {
                p1a[s][r] += acc[s][c][r] * a1;
                p2a[s][r] += acc[s][c][r] * a2;
            }
    }
    #pragma unroll
    for (int s = 0; s < 2; ++s)
        #pragma unroll
        for (int r = 0; r < 4; ++r) {
            float p1 = p1a[s][r], p2 = p2a[s][r];
            #pragma unroll
            for (int msk = 1; msk < 16; msk <<= 1) {
                p1 += __shfl_xor(p1, msk);
                p2 += __shfl_xor(p2, msk);
            }
            int row = row0 + s * 16 + (lane >> 4) * 4 + r;
            if ((lane & 15) == 0 && row < N_NODES) {
                s1[row] = p1;
                s2[row] = p2;
            }
        }

    // LDS-staged epilogue: coalesced uint4 stores of bf16 xw
    __syncthreads();                       // all waves done reading Bs
    char* slice = Bs + w * 16384;
    #pragma unroll
    for (int c = 0; c < 16; ++c) {
        #pragma unroll
        for (int s = 0; s < 2; ++s)
            #pragma unroll
            for (int r = 0; r < 4; ++r) {
                int lrow = s * 16 + (lane >> 4) * 4 + r;
                int col = c * 16 + (lane & 15);
                *(ushort*)(slice + lrow * 512 + col * 2) = (ushort)bf16rn(acc[s][c][r]);
            }
    }
    __syncthreads();
    #pragma unroll
    for (int i = 0; i < 16; ++i) {
        int flat = lane + 64 * i;
        int lrow = flat >> 5, c16 = flat & 31;
        int row = row0 + lrow;
        if (row < N_NODES) {
            uint4 v = *(const uint4*)(slice + lrow * 512 + c16 * 16);
            *(uint4*)(xwb + (size_t)row * DIM + c16 * 8) = v;
        }
    }
}

// ------------- rank: ealpha + histogram-with-rank, 2 incidences/thread -------------
__global__ void rank_kernel(
    const int* __restrict__ node_idx, const int* __restrict__ edge_idx,
    const float* __restrict__ s1, const float* __restrict__ s2,
    float* __restrict__ ealpha, unsigned* __restrict__ rank_pk,
    int* __restrict__ cnt_n, int* __restrict__ cnt_e)
{
    int e = blockIdx.x * blockDim.x + threadIdx.x;
    if (e >= RHALF) return;
    int e2 = e + RHALF;
    int n0 = node_idx[e],  h0 = edge_idx[e];
    int n1 = node_idx[e2], h1 = edge_idx[e2];
    float a0 = s1[n0] + s2[h0];
    float a1 = s1[n1] + s2[h1];
    a0 = a0 > 0.f ? a0 : NEG_SLOPE * a0;
    a1 = a1 > 0.f ? a1 : NEG_SLOPE * a1;
    ealpha[e]  = __expf(a0);              // no max-subtraction: |a| small, safe in f32
    ealpha[e2] = __expf(a1);
    unsigned rn0 = (unsigned)atomicAdd(cnt_n + n0, 1);
    unsigned re0 = (unsigned)atomicAdd(cnt_e + h0, 1);
    unsigned rn1 = (unsigned)atomicAdd(cnt_n + n1, 1);
    unsigned re1 = (unsigned)atomicAdd(cnt_e + h1, 1);
    rank_pk[e]  = (re0 << 16) | rn0;
    rank_pk[e2] = (re1 << 16) | rn1;
}

// ------------- scan phase 1 -------------
__global__ __launch_bounds__(1024) void scan_partial(
    const int* __restrict__ cnt_e, int* __restrict__ start_e, int* __restrict__ totals_e,
    const int* __restrict__ cnt_n, int* __restrict__ start_n, int* __restrict__ totals_n)
{
    int b = blockIdx.x;
    const int* cnt; int* start; int* totals; int n; int cb;
    if (b < EBLK) { cnt = cnt_e; start = start_e; totals = totals_e; n = M_EDGES; cb = b; }
    else          { cnt = cnt_n; start = start_n; totals = totals_n; n = N_NODES; cb = b - EBLK; }
    int tid = threadIdx.x, lane = tid & 63, wid = tid >> 6;
    int i = cb * 1024 + tid;
    int v = (i < n) ? cnt[i] : 0;
    #pragma unroll
    for (int off = 1; off < 64; off <<= 1) {
        int t = __shfl_up(v, off);
        if (lane >= off) v += t;
    }
    __shared__ int wsum[16];
    if (lane == 63) wsum[wid] = v;
    __syncthreads();
    if (wid == 0 && lane < 16) {
        int s = wsum[lane];
        #pragma unroll
        for (int off = 1; off < 16; off <<= 1) {
            int t = __shfl_up(s, off);
            if (lane >= off) s += t;
        }
        wsum[lane] = s;
    }
    __syncthreads();
    if (wid > 0) v += wsum[wid - 1];
    if (i < n) start[i + 1] = v;
    if (tid == 1023) totals[cb] = v;
}

// ------------- scan phase 2+3 fused -------------
__global__ __launch_bounds__(256) void scan_add(
    int* __restrict__ start_e, const int* __restrict__ totals_e,
    int* __restrict__ start_n, const int* __restrict__ totals_n)
{
    __shared__ int lboff_e[EBLK], lboff_n[NBLK];
    int tid = threadIdx.x;
    if (tid < 64) {
        int lane = tid;
        int ve0 = (lane < EBLK) ? totals_e[lane] : 0;
        int ve = ve0;
        #pragma unroll
        for (int off = 1; off < 64; off <<= 1) {
            int t = __shfl_up(ve, off);
            if (lane >= off) ve += t;
        }
        if (lane < EBLK) lboff_e[lane] = ve - ve0;
        int vn0 = (lane < NBLK) ? totals_n[lane] : 0;
        int vn = vn0;
        #pragma unroll
        for (int off = 1; off < 64; off <<= 1) {
            int t = __shfl_up(vn, off);
            if (lane >= off) vn += t;
        }
        if (lane < NBLK) lboff_n[lane] = vn - vn0;
    }
    __syncthreads();
    int id = blockIdx.x * 256 + tid;
    if (id == 0) start_e[0] = 0;
    if (id < M_EDGES) start_e[id + 1] += lboff_e[id >> 10];
    else if (id < M_EDGES + N_NODES) {
        int j = id - M_EDGES;
        if (j == 0) start_n[0] = 0;
        start_n[j + 1] += lboff_n[j >> 10];
    }
}

// ------------- place: CSR lists from precomputed ranks (no atomics) -------------
__global__ void place_kernel(
    const int* __restrict__ node_idx, const int* __restrict__ edge_idx,
    const unsigned* __restrict__ rank_pk,
    const int* __restrict__ start_e, const int* __restrict__ start_n,
    int* __restrict__ list_e, int* __restrict__ list_n)
{
    int e = blockIdx.x * blockDim.x + threadIdx.x;
    if (e >= N_INC) return;
    unsigned pk = rank_pk[e];
    list_e[start_e[edge_idx[e]] + (pk >> 16)] = e;
    list_n[start_n[node_idx[e]] + (pk & 0xFFFFu)] = e;
}

// ------------- rnorm: per-node esum via CSR gather (no atomics) -------------
__global__ void rnorm_kernel(
    const float* __restrict__ ealpha, const int* __restrict__ start_n,
    const int* __restrict__ list_n, float* __restrict__ rnorm)
{
    int n = blockIdx.x * blockDim.x + threadIdx.x;
    if (n >= N_NODES) return;
    int j0 = start_n[n], j1 = start_n[n + 1];
    float s = 0.f;
    for (int j = j0; j < j1; ++j) s += ealpha[list_n[j]];
    rnorm[n] = 1.f / (s + 1e-16f);
}

// ------------- stage 1: gather bf16 xw per hyperedge -> bf16 edge_feat -------------
__global__ __launch_bounds__(256) void stage1_kernel(
    const ushort* __restrict__ xwb, const int* __restrict__ node_idx,
    const float* __restrict__ ealpha, const float* __restrict__ rnorm,
    const int* __restrict__ start_e, const int* __restrict__ list_e,
    ushort* __restrict__ edge_feat)
{
    int h = blockIdx.x * 4 + (threadIdx.x >> 6);
    if (h >= M_EDGES) return;
    int lane = threadIdx.x & 63;
    int j0 = start_e[h], j1 = start_e[h + 1];
    float4 acc = make_float4(0.f, 0.f, 0.f, 0.f);
    float4 ac2 = make_float4(0.f, 0.f, 0.f, 0.f);
    for (int base = j0; base < j1; base += 64) {
        int cnt = min(64, j1 - base);
        float wv = 0.f; int nv = 0;
        if (lane < cnt) {
            int e = list_e[base + lane];
            int n_ = node_idx[e];
            wv = ealpha[e] * rnorm[n_];
            nv = n_;
        }
        int jj = 0;
        for (; jj + 4 <= cnt; jj += 4) {
            float wg0 = __shfl(wv, jj);     int n0 = __shfl(nv, jj);
            float wg1 = __shfl(wv, jj + 1); int n1 = __shfl(nv, jj + 1);
            float wg2 = __shfl(wv, jj + 2); int n2 = __shfl(nv, jj + 2);
            float wg3 = __shfl(wv, jj + 3); int n3 = __shfl(nv, jj + 3);
            uint2 p0 = *(const uint2*)(xwb + (size_t)n0 * DIM + lane * 4);
            uint2 p1 = *(const uint2*)(xwb + (size_t)n1 * DIM + lane * 4);
            uint2 p2 = *(const uint2*)(xwb + (size_t)n2 * DIM + lane * 4);
            uint2 p3 = *(const uint2*)(xwb + (size_t)n3 * DIM + lane * 4);
            float4 v0 = unp4(p0), v1 = unp4(p1), v2 = unp4(p2), v3 = unp4(p3);
            acc.x += wg0 * v0.x + wg1 * v1.x;  ac2.x += wg2 * v2.x + wg3 * v3.x;
            acc.y += wg0 * v0.y + wg1 * v1.y;  ac2.y += wg2 * v2.y + wg3 * v3.y;
            acc.z += wg0 * v0.z + wg1 * v1.z;  ac2.z += wg2 * v2.z + wg3 * v3.z;
            acc.w += wg0 * v0.w + wg1 * v1.w;  ac2.w += wg2 * v2.w + wg3 * v3.w;
        }
        for (; jj < cnt; ++jj) {
            float wg = __shfl(wv, jj); int n0 = __shfl(nv, jj);
            float4 v = unp4(*(const uint2*)(xwb + (size_t)n0 * DIM + lane * 4));
            acc.x += wg * v.x; acc.y += wg * v.y;
            acc.z += wg * v.z; acc.w += wg * v.w;
        }
    }
    acc.x += ac2.x; acc.y += ac2.y; acc.z += ac2.z; acc.w += ac2.w;
    float binv = (j1 > j0) ? 1.f / (float)(j1 - j0) : 0.f;
    uint2 p;
    p.x = bf16rn(acc.x * binv) | (bf16rn(acc.y * binv) << 16);
    p.y = bf16rn(acc.z * binv) | (bf16rn(acc.w * binv) << 16);
    *(uint2*)(edge_feat + (size_t)h * DIM + lane * 4) = p;
}

// ------------- stage 2: gather bf16 edge_feat per node; rnorm factors out -------------
__global__ __launch_bounds__(256) void stage2_kernel(
    const ushort* __restrict__ edge_feat, const int* __restrict__ edge_idx,
    const float* __restrict__ ealpha, const float* __restrict__ rnorm,
    const int* __restrict__ start_n, const int* __restrict__ list_n,
    const float* __restrict__ bias, float* __restrict__ out)
{
    int n = blockIdx.x * 4 + (threadIdx.x >> 6);
    if (n >= N_NODES) return;
    int lane = threadIdx.x & 63;
    int j0 = start_n[n], j1 = start_n[n + 1];
    float4 acc = make_float4(0.f, 0.f, 0.f, 0.f);
    float4 ac2 = make_float4(0.f, 0.f, 0.f, 0.f);
    for (int base = j0; base < j1; base += 64) {
        int cnt = min(64, j1 - base);
        float wv = 0.f; int hv = 0;
        if (lane < cnt) { int e = list_n[base + lane]; wv = ealpha[e]; hv = edge_idx[e]; }
        int jj = 0;
        for (; jj + 4 <= cnt; jj += 4) {
            float wg0 = __shfl(wv, jj);     int h0 = __shfl(hv, jj);
            float wg1 = __shfl(wv, jj + 1); int h1 = __shfl(hv, jj + 1);
            float wg2 = __shfl(wv, jj + 2); int h2 = __shfl(hv, jj + 2);
            float wg3 = __shfl(wv, jj + 3); int h3 = __shfl(hv, jj + 3);
            uint2 p0 = *(const uint2*)(edge_feat + (size_t)h0 * DIM + lane * 4);
            uint2 p1 = *(const uint2*)(edge_feat + (size_t)h1 * DIM + lane * 4);
            uint2 p2 = *(const uint2*)(edge_feat + (size_t)h2 * DIM + lane * 4);
            uint2 p3 = *(const uint2*)(edge_feat + (size_t)h3 * DIM + lane * 4);
            float4 v0 = unp4(p0), v1 = unp4(p1), v2 = unp4(p2), v3 = unp4(p3);
            acc.x += wg0 * v0.x + wg1 * v1.x;  ac2.x += wg2 * v2.x + wg3 * v3.x;
            acc.y += wg0 * v0.y + wg1 * v1.y;  ac2.y += wg2 * v2.y + wg3 * v3.y;
            acc.z += wg0 * v0.z + wg1 * v1.z;  ac2.z += wg2 * v2.z + wg3 * v3.z;
            acc.w += wg0 * v0.w + wg1 * v1.w;  ac2.w += wg2 * v2.w + wg3 * v3.w;
        }
        for (; jj < cnt; ++jj) {
            float wg = __shfl(wv, jj); int h0 = __shfl(hv, jj);
            float4 v = unp4(*(const uint2*)(edge_feat + (size_t)h0 * DIM + lane * 4));
            acc.x += wg * v.x; acc.y += wg * v.y;
            acc.z += wg * v.z; acc.w += wg * v.w;
        }
    }
    acc.x += ac2.x; acc.y += ac2.y; acc.z += ac2.z; acc.w += ac2.w;
    float sc = (j1 > j0) ? rnorm[n] / (float)(j1 - j0) : 0.f;   // dinv * rnorm
    float4 b = *(const float4*)(bias + lane * 4);
    acc.x = fmaf(acc.x, sc, b.x); acc.y = fmaf(acc.y, sc, b.y);
    acc.z = fmaf(acc.z, sc, b.z); acc.w = fmaf(acc.w, sc, b.w);
    *(float4*)(out + (size_t)n * DIM + lane * 4) = acc;
}

// ------------- BN column stats: float4 + LDS cross-wave reduce -------------
__global__ __launch_bounds__(256) void stats_kernel(
    const float* __restrict__ out, float* __restrict__ stats)
{
    __shared__ float lsum[4][256], lsq[4][256];
    int tid = threadIdx.x, lane = tid & 63, w = tid >> 6;
    int c4 = lane * 4;
    int rows_per = (N_NODES + gridDim.x - 1) / gridDim.x;
    int r0 = blockIdx.x * rows_per;
    int r1 = min(r0 + rows_per, N_NODES);
    float4 s = make_float4(0.f, 0.f, 0.f, 0.f);
    float4 q = make_float4(0.f, 0.f, 0.f, 0.f);
    for (int r = r0 + w; r < r1; r += 4) {
        float4 v = *(const float4*)(out + (size_t)r * DIM + c4);
        s.x += v.x; s.y += v.y; s.z += v.z; s.w += v.w;
        q.x += v.x * v.x; q.y += v.y * v.y; q.z += v.z * v.z; q.w += v.w * v.w;
    }
    *(float4*)&lsum[w][c4] = s;
    *(float4*)&lsq[w][c4] = q;
    __syncthreads();
    if (w == 0) {
        #pragma unroll
        for (int i = 1; i < 4; ++i) {
            s.x += lsum[i][c4]; s.y += lsum[i][c4 + 1]; s.z += lsum[i][c4 + 2]; s.w += lsum[i][c4 + 3];
            q.x += lsq[i][c4];  q.y += lsq[i][c4 + 1];  q.z += lsq[i][c4 + 2];  q.w += lsq[i][c4 + 3];
        }
        atomicAdd(stats + c4 + 0, s.x); atomicAdd(stats + c4 + 1, s.y);
        atomicAdd(stats + c4 + 2, s.z); atomicAdd(stats + c4 + 3, s.w);
        atomicAdd(stats + DIM + c4 + 0, q.x); atomicAdd(stats + DIM + c4 + 1, q.y);
        atomicAdd(stats + DIM + c4 + 2, q.z); atomicAdd(stats + DIM + c4 + 3, q.w);
    }
}

// ------------- BN apply + ELU with in-block prep, grid-stride float4 -------------
__global__ __launch_bounds__(256) void bn_kernel(
    float* __restrict__ out, const float* __restrict__ stats,
    const float* __restrict__ gamma, const float* __restrict__ beta)
{
    __shared__ float lsc[256], lsh[256];
    int tid = threadIdx.x;
    {
        float mu = stats[tid] * (1.f / N_NODES);
        float var = stats[DIM + tid] * (1.f / N_NODES) - mu * mu;
        float sc = gamma[tid] * rsqrtf(var + BN_EPS);
        lsc[tid] = sc;
        lsh[tid] = beta[tid] - mu * sc;
    }
    __syncthreads();
    int c4 = (tid & 63) * 4;                 // invariant: stride is multiple of 64
    float4 sc = *(const float4*)&lsc[c4];
    float4 sh = *(const float4*)&lsh[c4];
    for (int idx = blockIdx.x * 256 + tid; idx < N_NODES * DIM / 4; idx += gridDim.x * 256) {
        float4 v = ((float4*)out)[idx];
        v.x = fmaf(v.x, sc.x, sh.x); v.y = fmaf(v.y, sc.y, sh.y);
        v.z = fmaf(v.z, sc.z, sh.z); v.w = fmaf(v.w, sc.w, sh.w);
        v.x = v.x > 0.f ? v.x : __expf(v.x) - 1.f;
        v.y = v.y > 0.f ? v.y : __expf(v.y) - 1.f;
        v.z = v.z > 0.f ? v.z : __expf(v.z) - 1.f;
        v.w = v.w > 0.f ? v.w : __expf(v.w) - 1.f;
        ((float4*)out)[idx] = v;
    }
}

extern "C" void kernel_launch(void* const* d_in, const int* in_sizes, int n_in,
                              void* d_out, int out_size, void* d_ws, size_t ws_size,
                              hipStream_t stream)
{
    const float* x        = (const float*)d_in[0];
    const int*   node_idx = (const int*)d_in[1];
    const int*   edge_idx = (const int*)d_in[2];
    const float* W        = (const float*)d_in[4];
    const float* att      = (const float*)d_in[5];
    const float* bias     = (const float*)d_in[6];
    const float* gamma    = (const float*)d_in[7];
    const float* beta     = (const float*)d_in[8];
    float* out = (float*)d_out;
    ushort* xwb = (ushort*)d_out;     // bf16 xw in first 25.6 MB of d_out; overwritten by stage2

    ushort* edge_feat = (ushort*)d_ws;                          // M*DIM bf16
    // ---- zeroed block (contiguous, cleared by wt_kernel) ----
    int*   cnt_e   = (int*)(edge_feat + (size_t)M_EDGES * DIM); // M
    int*   cnt_n   = cnt_e + M_EDGES;                           // N
    float* stats   = (float*)(cnt_n + N_NODES);                 // 2*DIM
    // ---- not zeroed ----
    float* s1      = stats + 2 * DIM;                           // N
    float* s2      = s1 + N_NODES;                              // N
    float* ealpha  = s2 + N_NODES;                              // E
    unsigned* rank_pk = (unsigned*)(ealpha + N_INC);            // E
    float* rnorm   = (float*)(rank_pk + N_INC);                 // N
    int*   start_e = (int*)(rnorm + N_NODES);                   // M+1
    int*   start_n = start_e + M_EDGES + 1;                     // N+1
    int*   list_e  = start_n + N_NODES + 1;                     // E
    int*   list_n  = list_e + N_INC;                            // E
    ushort* WT     = (ushort*)(list_n + N_INC);                 // 256*256 bf16
    int*   totals_e = (int*)(WT + 256 * 256);                   // EBLK
    int*   totals_n = totals_e + EBLK;                          // NBLK

    wt_kernel<<<280, 256, 0, stream>>>(W, WT, cnt_e);
    gemm_persist<<<(N_NODES + GBM - 1) / GBM, 512, 0, stream>>>(x, WT, att, xwb, s1, s2);
    rank_kernel<<<(RHALF + 255) / 256, 256, 0, stream>>>(node_idx, edge_idx, s1, s2, ealpha, rank_pk, cnt_n, cnt_e);
    scan_partial<<<EBLK + NBLK, 1024, 0, stream>>>(cnt_e, start_e, totals_e, cnt_n, start_n, totals_n);
    scan_add<<<(M_EDGES + N_NODES + 255) / 256, 256, 0, stream>>>(start_e, totals_e, start_n, totals_n);
    place_kernel<<<(N_INC + 255) / 256, 256, 0, stream>>>(node_idx, edge_idx, rank_pk, start_e, start_n, list_e, list_n);
    rnorm_kernel<<<(N_NODES + 255) / 256, 256, 0, stream>>>(ealpha, start_n, list_n, rnorm);
    stage1_kernel<<<(M_EDGES + 3) / 4, 256, 0, stream>>>(xwb, node_idx, ealpha, rnorm, start_e, list_e, edge_feat);
    stage2_kernel<<<(N_NODES + 3) / 4, 256, 0, stream>>>(edge_feat, edge_idx, ealpha, rnorm, start_n, list_n, bias, out);
    stats_kernel<<<200, 256, 0, stream>>>(out, stats);
    bn_kernel<<<2048, 256, 0, stream>>>(out, stats, gamma, beta);
}